// Round 2
// baseline (1063.515 us; speedup 1.0000x reference)
//
#include <hip/hip_runtime.h>
#include <math.h>

#define B 256
#define L 64
#define D 100
#define S 12
#define NN 100000
#define E 99999
#define NEG -9e15f
#define LRELU 0.2f

__device__ __forceinline__ float lrelu(float x){ return x > 0.f ? x : LRELU*x; }

// ---------------- K0: pos_part[l][d] = sum_c pos[l][c]*w1[c][d] ----------------
__global__ void k0_pos(const float* __restrict__ pos, const float* __restrict__ w1,
                       float* __restrict__ pos_part){
    int l = blockIdx.x; int d = threadIdx.x;
    if (d >= D) return;
    float acc = 0.f;
    for (int c = 0; c < D; ++c) acc += pos[l*D+c] * w1[c*D+d];
    pos_part[l*D+d] = acc;
}

// ---------------- K1: h = emb[items]; sess = masked mean of emb[seq_features] ----------------
__global__ void k1_gather(const float* __restrict__ emb, const int* __restrict__ items,
                          const int* __restrict__ seqf, const float* __restrict__ mask,
                          float* __restrict__ h, float* __restrict__ sess){
    int b = blockIdx.x; int tid = threadIdx.x;
    for (int t = tid; t < L*D; t += blockDim.x){
        int l = t / D, d = t % D;
        h[(b*L+l)*D + d] = emb[(long)items[b*L+l]*D + d];
    }
    if (tid < D){
        float acc = 0.f, msum = 0.f;
        for (int l = 0; l < L; ++l){
            float mk = mask[b*L+l];
            acc  += emb[(long)seqf[b*L+l]*D + tid] * mk;
            msum += mk;
        }
        sess[b*D+tid] = acc / msum;
    }
}

// ---------------- K2: local aggregator, one block per (b,i) ----------------
__global__ __launch_bounds__(128) void k2_local(const float* __restrict__ h,
                         const int* __restrict__ adj,
                         const float* __restrict__ a0, const float* __restrict__ a1,
                         const float* __restrict__ a2, const float* __restrict__ a3,
                         float* __restrict__ hcomb){
    int bi = blockIdx.x; int b = bi / L, i = bi % L;
    int tid = threadIdx.x;
    __shared__ float hb[L][D+1];      // +1 pad: stride 101 kills bank conflicts
    __shared__ float a_lds[4*D];
    __shared__ float alpha[L];
    for (int t = tid; t < D; t += blockDim.x){
        a_lds[t] = a0[t]; a_lds[D+t] = a1[t]; a_lds[2*D+t] = a2[t]; a_lds[3*D+t] = a3[t];
    }
    for (int t = tid; t < L*D; t += blockDim.x){
        int l = t / D, d = t % D;
        hb[l][d] = h[(b*L+l)*D + d];
    }
    __syncthreads();
    if (tid < L){
        int k = adj[(b*L+i)*L + tid];
        float s;
        if (k >= 1 && k <= 4){
            const float* a = &a_lds[(k-1)*D];
            float acc = 0.f;
            for (int d = 0; d < D; ++d) acc += hb[i][d]*hb[tid][d]*a[d];
            s = lrelu(acc);
        } else s = NEG;
        float m = s;
        for (int off = 32; off >= 1; off >>= 1) m = fmaxf(m, __shfl_xor(m, off));
        float e = expf(s - m);                // all-NEG row -> exp(0)=1 -> uniform (matches jax)
        float sum = e;
        for (int off = 32; off >= 1; off >>= 1) sum += __shfl_xor(sum, off);
        alpha[tid] = e / sum;
    }
    __syncthreads();
    if (tid < D){
        float acc = 0.f;
        for (int j = 0; j < L; ++j) acc += alpha[j] * hb[j][tid];
        hcomb[(b*L+i)*D + tid] = acc;         // h_local; k3 adds h_global
    }
}

// ---------------- K3: global aggregator, one block per (b,l) ----------------
__global__ __launch_bounds__(128) void k3_global(const float* __restrict__ emb,
                          const float* __restrict__ h, const float* __restrict__ sess,
                          const int* __restrict__ items, const int* __restrict__ adj_all,
                          const float* __restrict__ num_w,
                          const float* __restrict__ gw1, const float* __restrict__ gw2,
                          const float* __restrict__ gw3,
                          float* __restrict__ hcomb){
    int bl = blockIdx.x; int b = bl / L;
    int tid = threadIdx.x;
    __shared__ float nbr[S][D];
    __shared__ float ain[S][D+1];
    __shared__ float t1[S][D];
    __shared__ float sess_l[D], hl[D], agg[D], att[S];
    __shared__ int   idxs[S];
    __shared__ float nbw[S];
    int item = items[bl];
    if (tid < S){ idxs[tid] = adj_all[item*S + tid]; nbw[tid] = num_w[item*S + tid]; }
    if (tid < D){ sess_l[tid] = sess[b*D+tid]; hl[tid] = h[bl*D + tid]; }
    __syncthreads();
    for (int t = tid; t < S*D; t += blockDim.x){
        int s = t / D, d = t % D;
        nbr[s][d] = emb[(long)idxs[s]*D + d];
    }
    __syncthreads();
    for (int t = tid; t < S*(D+1); t += blockDim.x){
        int s = t / (D+1), c = t % (D+1);
        ain[s][c] = (c < D) ? sess_l[c]*nbr[s][c] : nbw[s];
    }
    __syncthreads();
    if (tid < D){
        float acc[S];
        #pragma unroll
        for (int s=0;s<S;++s) acc[s]=0.f;
        for (int c = 0; c <= D; ++c){
            float g = gw1[c*D + tid];
            #pragma unroll
            for (int s=0;s<S;++s) acc[s] += ain[s][c]*g;
        }
        #pragma unroll
        for (int s=0;s<S;++s) t1[s][tid] = lrelu(acc[s]);
    }
    __syncthreads();
    if (tid < S){
        float acc = 0.f;
        for (int d=0; d<D; ++d) acc += t1[tid][d]*gw2[d];
        att[tid] = acc;
    }
    __syncthreads();
    if (tid == 0){
        float m = att[0];
        #pragma unroll
        for (int s=1;s<S;++s) m = fmaxf(m, att[s]);
        float sum = 0.f;
        #pragma unroll
        for (int s=0;s<S;++s){ att[s] = expf(att[s]-m); sum += att[s]; }
        #pragma unroll
        for (int s=0;s<S;++s) att[s] /= sum;
    }
    __syncthreads();
    if (tid < D){
        float ag = 0.f;
        #pragma unroll
        for (int s=0;s<S;++s) ag += att[s]*nbr[s][tid];
        agg[tid] = ag;
    }
    __syncthreads();
    if (tid < D){
        float acc = 0.f;
        for (int c=0;c<D;++c) acc += hl[c]*gw3[c*D+tid];
        for (int c=0;c<D;++c) acc += agg[c]*gw3[(D+c)*D+tid];
        hcomb[bl*D+tid] += fmaxf(acc, 0.f);   // h_comb = h_local + relu(...)
    }
}

// ---------------- K4: per-b predict head -> select[b][d] ----------------
__global__ __launch_bounds__(128) void k4_select(const float* __restrict__ hcomb,
                          const int* __restrict__ alias_in, const float* __restrict__ mask,
                          const float* __restrict__ pos_part, const float* __restrict__ w1,
                          const float* __restrict__ glu1_w, const float* __restrict__ glu2_w,
                          const float* __restrict__ glu2_b, const float* __restrict__ w2,
                          float* __restrict__ sel_out){
    int b = blockIdx.x; int tid = threadIdx.x;
    __shared__ float sh[L][D];
    __shared__ float hsd[D], nh1[D], nh2[D], mk[L], w2l[D];
    for (int t = tid; t < L*D; t += blockDim.x){
        int l = t / D, d = t % D;
        sh[l][d] = hcomb[(b*L + alias_in[b*L+l])*D + d];
    }
    if (tid < L) mk[tid] = mask[b*L+tid];
    if (tid < D) w2l[tid] = w2[tid];
    __syncthreads();
    float msum = 0.f;
    for (int l=0;l<L;++l) msum += mk[l];
    if (tid < D){
        float acc = 0.f;
        for (int l=0;l<L;++l) acc += sh[l][tid]*mk[l];
        hsd[tid] = acc / msum;
    }
    __syncthreads();
    float gatev = 0.f;
    if (tid < D){
        gatev = glu2_b[tid];
        for (int c=0;c<D;++c) gatev += hsd[c]*glu2_w[c*D+tid];
    }
    float sel = 0.f;
    for (int l=0;l<L;++l){
        __syncthreads();
        if (tid < D){
            float acc = pos_part[l*D+tid];
            for (int c=0;c<D;++c) acc += sh[l][c]*w1[(D+c)*D+tid];
            nh1[tid] = tanhf(acc);
        }
        __syncthreads();
        if (tid < D){
            float acc = gatev;
            for (int c=0;c<D;++c) acc += nh1[c]*glu1_w[c*D+tid];
            nh2[tid] = 1.f/(1.f+expf(-acc));
        }
        __syncthreads();
        float beta = 0.f;
        for (int d=0;d<D;++d) beta += nh2[d]*w2l[d];
        beta *= mk[l];
        if (tid < D) sel += beta * sh[l][tid];
    }
    if (tid < D) sel_out[b*D+tid] = sel;
}

// ---------------- K5: score = select @ emb[1:]^T  (64b x 256n tiles) ----------------
#define NT 256
__global__ __launch_bounds__(256) void k5_score(const float* __restrict__ emb,
                                                const float* __restrict__ sel,
                                                float* __restrict__ out){
    int tile = blockIdx.x; int bg = blockIdx.y;
    int tid = threadIdx.x;
    int ty = tid / 16, tx = tid % 16;
    __shared__ float Aa[64][D+1];
    __shared__ float Bn[64][D+1];
    for (int t = tid; t < 64*D; t += 256){
        int r = t/D, c = t%D;
        Aa[r][c] = sel[(bg*64 + r)*D + c];
    }
    int base_row = bg*64;
    for (int sub = 0; sub < 4; ++sub){
        int n0 = tile*NT + sub*64;
        __syncthreads();
        for (int t = tid; t < 64*D; t += 256){
            int r = t/D, c = t%D;
            int n = n0 + r;
            Bn[r][c] = (n < E) ? emb[(long)(1+n)*D + c] : 0.f;
        }
        __syncthreads();
        float acc[4][4] = {};
        for (int k = 0; k < D; ++k){
            float av[4], bv[4];
            #pragma unroll
            for (int i=0;i<4;++i) av[i] = Aa[ty*4+i][k];
            #pragma unroll
            for (int j=0;j<4;++j) bv[j] = Bn[tx*4+j][k];
            #pragma unroll
            for (int i=0;i<4;++i)
                #pragma unroll
                for (int j=0;j<4;++j) acc[i][j] += av[i]*bv[j];
        }
        #pragma unroll
        for (int i=0;i<4;++i){
            int row = base_row + ty*4+i;
            #pragma unroll
            for (int j=0;j<4;++j){
                int col = n0 + tx*4+j;
                if (col < E) out[(long)row*E + col] = acc[i][j];
            }
        }
    }
}

// ---------------- K6/K7: softmax stats (tiled online max/sum) ----------------
#define TS 16384
#define NTILES 7
__global__ __launch_bounds__(256) void k6_stats(const float* __restrict__ out,
                                                float* __restrict__ stats){
    int t = blockIdx.x, b = blockIdx.y;
    int tid = threadIdx.x;
    int start = t*TS, end = start+TS < E ? start+TS : E;
    float m = -INFINITY, s = 0.f;
    for (int n = start + tid; n < end; n += 256){
        float v = out[(long)b*E + n];
        if (v > m){ s = s*expf(m - v) + 1.f; m = v; }
        else        s += expf(v - m);
    }
    __shared__ float ms[256], ss[256];
    ms[tid] = m; ss[tid] = s;
    __syncthreads();
    for (int off = 128; off >= 1; off >>= 1){
        if (tid < off){
            float m1 = ms[tid], s1 = ss[tid];
            float m2 = ms[tid+off], s2 = ss[tid+off];
            float mm = fmaxf(m1, m2);
            float sn = 0.f;
            if (m1 > -INFINITY) sn += s1*expf(m1-mm);
            if (m2 > -INFINITY) sn += s2*expf(m2-mm);
            ms[tid] = mm; ss[tid] = sn;
        }
        __syncthreads();
    }
    if (tid == 0){ stats[(b*NTILES+t)*2] = ms[0]; stats[(b*NTILES+t)*2+1] = ss[0]; }
}

__global__ void k7_combine(const float* __restrict__ stats, float* __restrict__ MS){
    int b = threadIdx.x;
    float m = -INFINITY, s = 0.f;
    for (int t=0;t<NTILES;++t){
        float m2 = stats[(b*NTILES+t)*2], s2 = stats[(b*NTILES+t)*2+1];
        float mm = fmaxf(m, m2);
        float sn = 0.f;
        if (m  > -INFINITY) sn += s *expf(m -mm);
        if (m2 > -INFINITY) sn += s2*expf(m2-mm);
        m = mm; s = sn;
    }
    MS[b*2] = m; MS[b*2+1] = 1.f/s;
}

// ---------------- K8: normalize in place ----------------
__global__ __launch_bounds__(256) void k8_norm(float* __restrict__ out,
                                               const float* __restrict__ MS){
    int b = blockIdx.y;
    int n = blockIdx.x*256 + threadIdx.x;
    if (n < E){
        float m = MS[b*2], invs = MS[b*2+1];
        long i = (long)b*E + n;
        out[i] = expf(out[i] - m) * invs;
    }
}

extern "C" void kernel_launch(void* const* d_in, const int* in_sizes, int n_in,
                              void* d_out, int out_size, void* d_ws, size_t ws_size,
                              hipStream_t stream) {
    const float* emb       = (const float*)d_in[0];
    const float* pos_table = (const float*)d_in[1];
    const float* w1        = (const float*)d_in[2];
    const float* w2        = (const float*)d_in[3];
    const float* glu1_w    = (const float*)d_in[4];
    const float* glu2_w    = (const float*)d_in[5];
    const float* glu2_b    = (const float*)d_in[6];
    const float* a0        = (const float*)d_in[7];
    const float* a1        = (const float*)d_in[8];
    const float* a2        = (const float*)d_in[9];
    const float* a3        = (const float*)d_in[10];
    const float* gw1       = (const float*)d_in[11];
    const float* gw2       = (const float*)d_in[12];
    const float* gw3       = (const float*)d_in[13];
    const float* num_w     = (const float*)d_in[14];
    const float* mask      = (const float*)d_in[15];
    const int*   alias_in  = (const int*)d_in[16];
    const int*   adj       = (const int*)d_in[17];
    const int*   items     = (const int*)d_in[18];
    const int*   seqf      = (const int*)d_in[19];
    const int*   adj_all   = (const int*)d_in[20];

    float* ws       = (float*)d_ws;
    float* h        = ws;                       // B*L*D
    float* hcomb    = h + B*L*D;                // B*L*D
    float* sess     = hcomb + B*L*D;            // B*D
    float* pos_part = sess + B*D;               // L*D
    float* sel      = pos_part + L*D;           // B*D
    float* stats    = sel + B*D;                // B*NTILES*2
    float* MS       = stats + B*NTILES*2;       // B*2

    float* out = (float*)d_out;

    k0_pos   <<<dim3(L), dim3(128), 0, stream>>>(pos_table, w1, pos_part);
    k1_gather<<<dim3(B), dim3(128), 0, stream>>>(emb, items, seqf, mask, h, sess);
    k2_local <<<dim3(B*L), dim3(128), 0, stream>>>(h, adj, a0, a1, a2, a3, hcomb);
    k3_global<<<dim3(B*L), dim3(128), 0, stream>>>(emb, h, sess, items, adj_all, num_w,
                                                   gw1, gw2, gw3, hcomb);
    k4_select<<<dim3(B), dim3(128), 0, stream>>>(hcomb, alias_in, mask, pos_part, w1,
                                                 glu1_w, glu2_w, glu2_b, w2, sel);
    k5_score <<<dim3((E + NT - 1)/NT, 4), dim3(256), 0, stream>>>(emb, sel, out);
    k6_stats <<<dim3(NTILES, B), dim3(256), 0, stream>>>(out, stats);
    k7_combine<<<dim3(1), dim3(B), 0, stream>>>(stats, MS);
    k8_norm  <<<dim3((E + 255)/256, B), dim3(256), 0, stream>>>(out, MS);
}

// Round 3
// 894.373 us; speedup vs baseline: 1.1891x; 1.1891x over previous
//
#include <hip/hip_runtime.h>
#include <math.h>

#define B 256
#define L 64
#define D 100
#define S 12
#define NN 100000
#define E 99999
#define NEG -9e15f
#define LRELU 0.2f
#define M3A (B*L*S)          // 196608 rows for k3a
#define NT5 782              // ceil(E/128) col tiles in k5

__device__ __forceinline__ float lrelu(float x){ return x > 0.f ? x : LRELU*x; }

// ---------------- K0: pos_part[l][d] = sum_c pos[l][c]*w1[c][d] ----------------
__global__ void k0_pos(const float* __restrict__ pos, const float* __restrict__ w1,
                       float* __restrict__ pos_part){
    int l = blockIdx.x; int d = threadIdx.x;
    if (d >= D) return;
    float acc = 0.f;
    for (int c = 0; c < D; ++c) acc += pos[l*D+c] * w1[c*D+d];
    pos_part[l*D+d] = acc;
}

// ---------------- K1: h = emb[items]; sess = masked mean of emb[seq_features] ----------------
__global__ void k1_gather(const float* __restrict__ emb, const int* __restrict__ items,
                          const int* __restrict__ seqf, const float* __restrict__ mask,
                          float* __restrict__ h, float* __restrict__ sess){
    int b = blockIdx.x; int tid = threadIdx.x;
    for (int t = tid; t < L*D; t += blockDim.x){
        int l = t / D, d = t % D;
        h[(b*L+l)*D + d] = emb[(long)items[b*L+l]*D + d];
    }
    if (tid < D){
        float acc = 0.f, msum = 0.f;
        for (int l = 0; l < L; ++l){
            float mk = mask[b*L+l];
            acc  += emb[(long)seqf[b*L+l]*D + tid] * mk;
            msum += mk;
        }
        sess[b*D+tid] = acc / msum;
    }
}

// ---------------- K2: local aggregator, one block per (b,i) ----------------
__global__ __launch_bounds__(128) void k2_local(const float* __restrict__ h,
                         const int* __restrict__ adj,
                         const float* __restrict__ a0, const float* __restrict__ a1,
                         const float* __restrict__ a2, const float* __restrict__ a3,
                         float* __restrict__ hcomb){
    int bi = blockIdx.x; int b = bi / L, i = bi % L;
    int tid = threadIdx.x;
    __shared__ float hb[L][D+1];
    __shared__ float a_lds[4*D];
    __shared__ float alpha[L];
    for (int t = tid; t < D; t += blockDim.x){
        a_lds[t] = a0[t]; a_lds[D+t] = a1[t]; a_lds[2*D+t] = a2[t]; a_lds[3*D+t] = a3[t];
    }
    for (int t = tid; t < L*D; t += blockDim.x){
        int l = t / D, d = t % D;
        hb[l][d] = h[(b*L+l)*D + d];
    }
    __syncthreads();
    if (tid < L){
        int k = adj[(b*L+i)*L + tid];
        float s;
        if (k >= 1 && k <= 4){
            const float* a = &a_lds[(k-1)*D];
            float acc = 0.f;
            for (int d = 0; d < D; ++d) acc += hb[i][d]*hb[tid][d]*a[d];
            s = lrelu(acc);
        } else s = NEG;
        float m = s;
        for (int off = 32; off >= 1; off >>= 1) m = fmaxf(m, __shfl_xor(m, off));
        float e = expf(s - m);
        float sum = e;
        for (int off = 32; off >= 1; off >>= 1) sum += __shfl_xor(sum, off);
        alpha[tid] = e / sum;
    }
    __syncthreads();
    if (tid < D){
        float acc = 0.f;
        for (int j = 0; j < L; ++j) acc += alpha[j] * hb[j][tid];
        hcomb[(b*L+i)*D + tid] = acc;         // h_local; k3c adds h_global
    }
}

// ---------------- K3a: att logits. GEMM M=196608 K=104 N=128(pad), fused lrelu+gw2 reduce ----
// rows r = bl*S + s; 64-row tiles (one b per tile since 768%64==0)
__global__ __launch_bounds__(256) void k3a_logits(const float* __restrict__ emb,
                          const float* __restrict__ sess,
                          const int* __restrict__ items, const int* __restrict__ adj_all,
                          const float* __restrict__ num_w,
                          const float* __restrict__ gw1, const float* __restrict__ gw2,
                          float* __restrict__ att_l){
    __shared__ __align__(16) float As[52*64];
    __shared__ __align__(16) float Bs[52*128];
    __shared__ float ss[104];
    __shared__ int   idxr[64];
    __shared__ float nbwr[64];
    __shared__ float gw2l[128];
    int tid = threadIdx.x;
    int tx = tid & 15, ty = tid >> 4;
    int r0 = blockIdx.x * 64;
    int b  = r0 / (L*S);

    if (tid < 64){
        int r = r0 + tid;
        int bl = r / S, s = r - bl*S;
        int it = items[bl];
        idxr[tid] = adj_all[it*S + s];
        nbwr[tid] = num_w[it*S + s];
    }
    if (tid < 104) ss[tid] = (tid < D) ? sess[b*D + tid] : 0.f;
    if (tid < 128) gw2l[tid] = (tid < D) ? gw2[tid] : 0.f;
    __syncthreads();

    float acc[4][8];
    #pragma unroll
    for (int i=0;i<4;++i)
        #pragma unroll
        for (int j=0;j<8;++j) acc[i][j] = 0.f;

    for (int chunk = 0; chunk < 2; ++chunk){
        int c0 = chunk*52;
        // stage A (k-major): As[cc][rl] = ain[r0+rl][c0+cc]
        for (int e = tid; e < 64*13; e += 256){
            int rl = e & 63, cq = e >> 6;
            int cb = c0 + cq*4;
            float vx=0.f, vy=0.f, vz=0.f, vw=0.f;
            if (cb < D){
                const float4 v = *(const float4*)&emb[(long)idxr[rl]*D + cb];
                vx = v.x*ss[cb]; vy = v.y*ss[cb+1]; vz = v.z*ss[cb+2]; vw = v.w*ss[cb+3];
            } else if (cb == D){
                vx = nbwr[rl];
            }
            As[(cq*4+0)*64 + rl] = vx;
            As[(cq*4+1)*64 + rl] = vy;
            As[(cq*4+2)*64 + rl] = vz;
            As[(cq*4+3)*64 + rl] = vw;
        }
        // stage B: Bs[cc][d] = gw1[c0+cc][d]
        for (int e = tid; e < 52*128; e += 256){
            int d = e & 127, cc = e >> 7;
            int c = c0 + cc;
            Bs[cc*128 + d] = (c <= D && d < D) ? gw1[c*D + d] : 0.f;
        }
        __syncthreads();
        for (int k = 0; k < 52; ++k){
            float4 a  = *(const float4*)&As[k*64 + ty*4];
            float4 b0 = *(const float4*)&Bs[k*128 + tx*4];
            float4 b1 = *(const float4*)&Bs[k*128 + 64 + tx*4];
            float av[4] = {a.x,a.y,a.z,a.w};
            float bv[8] = {b0.x,b0.y,b0.z,b0.w,b1.x,b1.y,b1.z,b1.w};
            #pragma unroll
            for (int i=0;i<4;++i)
                #pragma unroll
                for (int j=0;j<8;++j) acc[i][j] += av[i]*bv[j];
        }
        __syncthreads();
    }
    // epilogue: logit[row] = sum_d lrelu(t1)*gw2[d], reduce across tx lanes
    float g[8];
    #pragma unroll
    for (int j=0;j<8;++j) g[j] = gw2l[(j<4) ? (tx*4+j) : (64 + tx*4 + (j-4))];
    #pragma unroll
    for (int i=0;i<4;++i){
        float p = 0.f;
        #pragma unroll
        for (int j=0;j<8;++j) p += lrelu(acc[i][j]) * g[j];
        #pragma unroll
        for (int off=1; off<16; off<<=1) p += __shfl_xor(p, off);
        if (tx == 0) att_l[r0 + ty*4 + i] = p;
    }
}

// ---------------- K3b: softmax(12) + agg[bl][d] = sum_s att*nbr ----------------
__global__ __launch_bounds__(256) void k3b_agg(const float* __restrict__ emb,
                          const int* __restrict__ items, const int* __restrict__ adj_all,
                          const float* __restrict__ att_l,
                          float* __restrict__ agg){
    int p = blockIdx.x*2 + (threadIdx.x >> 7);   // bl index
    int t = threadIdx.x & 127;
    float lg[S];
    float m = -INFINITY;
    #pragma unroll
    for (int s=0;s<S;++s){ lg[s] = att_l[p*S + s]; m = fmaxf(m, lg[s]); }
    float sum = 0.f;
    #pragma unroll
    for (int s=0;s<S;++s){ lg[s] = expf(lg[s]-m); sum += lg[s]; }
    float inv = 1.f/sum;
    if (t < D){
        int it = items[p];
        float acc = 0.f;
        #pragma unroll
        for (int s=0;s<S;++s){
            int idx = adj_all[it*S + s];
            acc += lg[s]*inv * emb[(long)idx*D + t];
        }
        agg[p*D + t] = acc;
    }
}

// ---------------- K3c: hcomb += relu([h|agg] @ gw3). M=16384 K=208(pad) N=128(pad) ---------
__global__ __launch_bounds__(256) void k3c_hg(const float* __restrict__ h,
                          const float* __restrict__ agg, const float* __restrict__ gw3,
                          float* __restrict__ hcomb){
    __shared__ __align__(16) float As[52*64];
    __shared__ __align__(16) float Bs[52*128];
    int tid = threadIdx.x;
    int tx = tid & 15, ty = tid >> 4;
    int r0 = blockIdx.x * 64;

    float acc[4][8];
    #pragma unroll
    for (int i=0;i<4;++i)
        #pragma unroll
        for (int j=0;j<8;++j) acc[i][j] = 0.f;

    for (int chunk = 0; chunk < 4; ++chunk){
        int c0 = chunk*52;
        for (int e = tid; e < 64*13; e += 256){
            int rl = e & 63, cq = e >> 6;
            int cb = c0 + cq*4;
            float4 v = {0.f,0.f,0.f,0.f};
            if (cb < D)            v = *(const float4*)&h[(long)(r0+rl)*D + cb];
            else if (cb < 2*D)     v = *(const float4*)&agg[(long)(r0+rl)*D + (cb-D)];
            As[(cq*4+0)*64 + rl] = v.x;
            As[(cq*4+1)*64 + rl] = v.y;
            As[(cq*4+2)*64 + rl] = v.z;
            As[(cq*4+3)*64 + rl] = v.w;
        }
        for (int e = tid; e < 52*128; e += 256){
            int d = e & 127, cc = e >> 7;
            int c = c0 + cc;
            Bs[cc*128 + d] = (c < 2*D && d < D) ? gw3[c*D + d] : 0.f;
        }
        __syncthreads();
        for (int k = 0; k < 52; ++k){
            float4 a  = *(const float4*)&As[k*64 + ty*4];
            float4 b0 = *(const float4*)&Bs[k*128 + tx*4];
            float4 b1 = *(const float4*)&Bs[k*128 + 64 + tx*4];
            float av[4] = {a.x,a.y,a.z,a.w};
            float bv[8] = {b0.x,b0.y,b0.z,b0.w,b1.x,b1.y,b1.z,b1.w};
            #pragma unroll
            for (int i=0;i<4;++i)
                #pragma unroll
                for (int j=0;j<8;++j) acc[i][j] += av[i]*bv[j];
        }
        __syncthreads();
    }
    #pragma unroll
    for (int i=0;i<4;++i){
        int r = r0 + ty*4 + i;
        #pragma unroll
        for (int j=0;j<8;++j){
            int d = (j<4) ? (tx*4+j) : (64 + tx*4 + (j-4));
            if (d < D){
                long o = (long)r*D + d;
                hcomb[o] += fmaxf(acc[i][j], 0.f);
            }
        }
    }
}

// ---------------- K4: per-b predict head -> select[b][d] ----------------
__global__ __launch_bounds__(128) void k4_select(const float* __restrict__ hcomb,
                          const int* __restrict__ alias_in, const float* __restrict__ mask,
                          const float* __restrict__ pos_part, const float* __restrict__ w1,
                          const float* __restrict__ glu1_w, const float* __restrict__ glu2_w,
                          const float* __restrict__ glu2_b, const float* __restrict__ w2,
                          float* __restrict__ sel_out){
    int b = blockIdx.x; int tid = threadIdx.x;
    __shared__ float sh[L][D];
    __shared__ float hsd[D], nh1[D], nh2[D], mk[L], w2l[D];
    for (int t = tid; t < L*D; t += blockDim.x){
        int l = t / D, d = t % D;
        sh[l][d] = hcomb[(b*L + alias_in[b*L+l])*D + d];
    }
    if (tid < L) mk[tid] = mask[b*L+tid];
    if (tid < D) w2l[tid] = w2[tid];
    __syncthreads();
    float msum = 0.f;
    for (int l=0;l<L;++l) msum += mk[l];
    if (tid < D){
        float acc = 0.f;
        for (int l=0;l<L;++l) acc += sh[l][tid]*mk[l];
        hsd[tid] = acc / msum;
    }
    __syncthreads();
    float gatev = 0.f;
    if (tid < D){
        gatev = glu2_b[tid];
        for (int c=0;c<D;++c) gatev += hsd[c]*glu2_w[c*D+tid];
    }
    float sel = 0.f;
    for (int l=0;l<L;++l){
        __syncthreads();
        if (tid < D){
            float acc = pos_part[l*D+tid];
            for (int c=0;c<D;++c) acc += sh[l][c]*w1[(D+c)*D+tid];
            nh1[tid] = tanhf(acc);
        }
        __syncthreads();
        if (tid < D){
            float acc = gatev;
            for (int c=0;c<D;++c) acc += nh1[c]*glu1_w[c*D+tid];
            nh2[tid] = 1.f/(1.f+expf(-acc));
        }
        __syncthreads();
        float beta = 0.f;
        for (int d=0;d<D;++d) beta += nh2[d]*w2l[d];
        beta *= mk[l];
        if (tid < D) sel += beta * sh[l][tid];
    }
    if (tid < D) sel_out[b*D+tid] = sel;
}

// ---------------- K5: score tile GEMM + fused per-row online softmax stats ----------------
// M=256 (4 row-groups of 64), N=99999 (128-col tiles), K=100 (pad 104)
__global__ __launch_bounds__(256) void k5_score(const float* __restrict__ emb,
                                                const float* __restrict__ sel,
                                                float* __restrict__ out,
                                                float* __restrict__ pstats){
    __shared__ __align__(16) float As[52*64];
    __shared__ __align__(16) float Bs[52*128];
    int tid = threadIdx.x;
    int tx = tid & 15, ty = tid >> 4;
    int n0 = blockIdx.x * 128;
    int m0 = blockIdx.y * 64;

    float acc[4][8];
    #pragma unroll
    for (int i=0;i<4;++i)
        #pragma unroll
        for (int j=0;j<8;++j) acc[i][j] = 0.f;

    for (int chunk = 0; chunk < 2; ++chunk){
        int c0 = chunk*52;
        for (int e = tid; e < 64*13; e += 256){
            int rl = e & 63, cq = e >> 6;
            int cb = c0 + cq*4;
            float4 v = {0.f,0.f,0.f,0.f};
            if (cb < D) v = *(const float4*)&sel[(long)(m0+rl)*D + cb];
            As[(cq*4+0)*64 + rl] = v.x;
            As[(cq*4+1)*64 + rl] = v.y;
            As[(cq*4+2)*64 + rl] = v.z;
            As[(cq*4+3)*64 + rl] = v.w;
        }
        for (int e = tid; e < 128*13; e += 256){
            int nl = e & 127, cq = e >> 7;
            int cb = c0 + cq*4;
            int n = n0 + nl;
            float4 v = {0.f,0.f,0.f,0.f};
            if (cb < D && n < E) v = *(const float4*)&emb[(long)(1+n)*D + cb];
            Bs[(cq*4+0)*128 + nl] = v.x;
            Bs[(cq*4+1)*128 + nl] = v.y;
            Bs[(cq*4+2)*128 + nl] = v.z;
            Bs[(cq*4+3)*128 + nl] = v.w;
        }
        __syncthreads();
        for (int k = 0; k < 52; ++k){
            float4 a  = *(const float4*)&As[k*64 + ty*4];
            float4 b0 = *(const float4*)&Bs[k*128 + tx*4];
            float4 b1 = *(const float4*)&Bs[k*128 + 64 + tx*4];
            float av[4] = {a.x,a.y,a.z,a.w};
            float bv[8] = {b0.x,b0.y,b0.z,b0.w,b1.x,b1.y,b1.z,b1.w};
            #pragma unroll
            for (int i=0;i<4;++i)
                #pragma unroll
                for (int j=0;j<8;++j) acc[i][j] += av[i]*bv[j];
        }
        __syncthreads();
    }
    bool fullTile = (n0 + 128 <= E);
    #pragma unroll
    for (int i=0;i<4;++i){
        int m = m0 + ty*4 + i;
        long rowo = (long)m*E;
        // store scores
        if (fullTile){
            *(float4*)&out[rowo + n0 + tx*4]      = *(float4*)&acc[i][0];
            *(float4*)&out[rowo + n0 + 64 + tx*4] = *(float4*)&acc[i][4];
        } else {
            #pragma unroll
            for (int j=0;j<8;++j){
                int n = n0 + ((j<4) ? (tx*4+j) : (64 + tx*4 + (j-4)));
                if (n < E) out[rowo + n] = acc[i][j];
            }
        }
        // online stats over this thread's 8 cols
        float mx = -INFINITY, sm = 0.f;
        #pragma unroll
        for (int j=0;j<8;++j){
            int n = n0 + ((j<4) ? (tx*4+j) : (64 + tx*4 + (j-4)));
            if (n < E){
                float v = acc[i][j];
                if (v > mx){ sm = sm*expf(mx - v) + 1.f; mx = v; }
                else         sm += expf(v - mx);
            }
        }
        // merge across the 16 tx lanes
        #pragma unroll
        for (int off=1; off<16; off<<=1){
            float mo = __shfl_xor(mx, off);
            float so = __shfl_xor(sm, off);
            float mm = fmaxf(mx, mo);
            float sn = 0.f;
            if (mx > -INFINITY) sn += sm*expf(mx-mm);
            if (mo > -INFINITY) sn += so*expf(mo-mm);
            mx = mm; sm = sn;
        }
        if (tx == 0){
            long o = ((long)m*NT5 + blockIdx.x)*2;
            pstats[o] = mx; pstats[o+1] = sm;
        }
    }
}

// ---------------- K7: combine per-row partial stats ----------------
__global__ __launch_bounds__(256) void k7_combine(const float* __restrict__ pstats,
                                                  float* __restrict__ MS){
    int row = blockIdx.x;
    int tid = threadIdx.x;
    float m = -INFINITY, s = 0.f;
    for (int t = tid; t < NT5; t += 256){
        long o = ((long)row*NT5 + t)*2;
        float m2 = pstats[o], s2 = pstats[o+1];
        float mm = fmaxf(m, m2);
        float sn = 0.f;
        if (m  > -INFINITY) sn += s *expf(m -mm);
        if (m2 > -INFINITY) sn += s2*expf(m2-mm);
        m = mm; s = sn;
    }
    __shared__ float ms[256], ss[256];
    ms[tid] = m; ss[tid] = s;
    __syncthreads();
    for (int off = 128; off >= 1; off >>= 1){
        if (tid < off){
            float m1 = ms[tid], s1 = ss[tid];
            float m2 = ms[tid+off], s2 = ss[tid+off];
            float mm = fmaxf(m1, m2);
            float sn = 0.f;
            if (m1 > -INFINITY) sn += s1*expf(m1-mm);
            if (m2 > -INFINITY) sn += s2*expf(m2-mm);
            ms[tid] = mm; ss[tid] = sn;
        }
        __syncthreads();
    }
    if (tid == 0){ MS[row*2] = ms[0]; MS[row*2+1] = 1.f/ss[0]; }
}

// ---------------- K8: normalize in place ----------------
__global__ __launch_bounds__(256) void k8_norm(float* __restrict__ out,
                                               const float* __restrict__ MS){
    int b = blockIdx.y;
    int n = blockIdx.x*256 + threadIdx.x;
    if (n < E){
        float m = MS[b*2], invs = MS[b*2+1];
        long i = (long)b*E + n;
        out[i] = expf(out[i] - m) * invs;
    }
}

extern "C" void kernel_launch(void* const* d_in, const int* in_sizes, int n_in,
                              void* d_out, int out_size, void* d_ws, size_t ws_size,
                              hipStream_t stream) {
    const float* emb       = (const float*)d_in[0];
    const float* pos_table = (const float*)d_in[1];
    const float* w1        = (const float*)d_in[2];
    const float* w2        = (const float*)d_in[3];
    const float* glu1_w    = (const float*)d_in[4];
    const float* glu2_w    = (const float*)d_in[5];
    const float* glu2_b    = (const float*)d_in[6];
    const float* a0        = (const float*)d_in[7];
    const float* a1        = (const float*)d_in[8];
    const float* a2        = (const float*)d_in[9];
    const float* a3        = (const float*)d_in[10];
    const float* gw1       = (const float*)d_in[11];
    const float* gw2       = (const float*)d_in[12];
    const float* gw3       = (const float*)d_in[13];
    const float* num_w     = (const float*)d_in[14];
    const float* mask      = (const float*)d_in[15];
    const int*   alias_in  = (const int*)d_in[16];
    const int*   adj       = (const int*)d_in[17];
    const int*   items     = (const int*)d_in[18];
    const int*   seqf      = (const int*)d_in[19];
    const int*   adj_all   = (const int*)d_in[20];

    float* ws       = (float*)d_ws;
    float* h        = ws;                       // B*L*D          = 1,638,400
    float* hcomb    = h + B*L*D;                // B*L*D          = 1,638,400
    float* sess     = hcomb + B*L*D;            // B*D            = 25,600
    float* pos_part = sess + B*D;               // L*D            = 6,400
    float* sel      = pos_part + L*D;           // B*D            = 25,600
    float* att_l    = sel + B*D;                // M3A            = 196,608
    float* agg      = att_l + M3A;              // B*L*D          = 1,638,400
    float* pstats   = agg + B*L*D;              // B*NT5*2        = 400,384
    float* MS       = pstats + B*NT5*2;         // B*2            = 512

    float* out = (float*)d_out;

    k0_pos    <<<dim3(L), dim3(128), 0, stream>>>(pos_table, w1, pos_part);
    k1_gather <<<dim3(B), dim3(128), 0, stream>>>(emb, items, seqf, mask, h, sess);
    k2_local  <<<dim3(B*L), dim3(128), 0, stream>>>(h, adj, a0, a1, a2, a3, hcomb);
    k3a_logits<<<dim3(M3A/64), dim3(256), 0, stream>>>(emb, sess, items, adj_all, num_w,
                                                       gw1, gw2, att_l);
    k3b_agg   <<<dim3(B*L/2), dim3(256), 0, stream>>>(emb, items, adj_all, att_l, agg);
    k3c_hg    <<<dim3(B*L/64), dim3(256), 0, stream>>>(h, agg, gw3, hcomb);
    k4_select <<<dim3(B), dim3(128), 0, stream>>>(hcomb, alias_in, mask, pos_part, w1,
                                                  glu1_w, glu2_w, glu2_b, w2, sel);
    k5_score  <<<dim3(NT5, 4), dim3(256), 0, stream>>>(emb, sel, out, pstats);
    k7_combine<<<dim3(B), dim3(256), 0, stream>>>(pstats, MS);
    k8_norm   <<<dim3((E + 255)/256, B), dim3(256), 0, stream>>>(out, MS);
}

// Round 6
// 665.927 us; speedup vs baseline: 1.5970x; 1.3430x over previous
//
#include <hip/hip_runtime.h>
#include <math.h>

#define B 256
#define L 64
#define D 100
#define S 12
#define NN 100000
#define E 99999
#define NEG -9e15f
#define LRELU 0.2f
#define M3A (B*L*S)          // 196608 rows for k3a
#define NT5 782              // ceil(E/128) col tiles in k5

__device__ __forceinline__ float lrelu(float x){ return x > 0.f ? x : LRELU*x; }

// ---------------- K0: pos_part[l][d] = sum_c pos[l][c]*w1[c][d] ----------------
__global__ void k0_pos(const float* __restrict__ pos, const float* __restrict__ w1,
                       float* __restrict__ pos_part){
    int l = blockIdx.x; int d = threadIdx.x;
    if (d >= D) return;
    float acc = 0.f;
    for (int c = 0; c < D; ++c) acc += pos[l*D+c] * w1[c*D+d];
    pos_part[l*D+d] = acc;
}

// ---------------- K1: h = emb[items]; sess = masked mean of emb[seq_features] ----------------
__global__ void k1_gather(const float* __restrict__ emb, const int* __restrict__ items,
                          const int* __restrict__ seqf, const float* __restrict__ mask,
                          float* __restrict__ h, float* __restrict__ sess){
    int b = blockIdx.x; int tid = threadIdx.x;
    for (int t = tid; t < L*D; t += blockDim.x){
        int l = t / D, d = t % D;
        h[(b*L+l)*D + d] = emb[(long)items[b*L+l]*D + d];
    }
    if (tid < D){
        float acc = 0.f, msum = 0.f;
        for (int l = 0; l < L; ++l){
            float mk = mask[b*L+l];
            acc  += emb[(long)seqf[b*L+l]*D + tid] * mk;
            msum += mk;
        }
        sess[b*D+tid] = acc / msum;
    }
}

// ---------------- K2: local aggregator, one block per b ----------------
// Phase 1: all four E_k = (h .* a_k) h^T in registers (4x4 tile / thread);
// select via adj, masked row-softmax via 16-lane shuffles; alpha -> LDS.
// Phase 3: h_local = alpha @ h.
__global__ __launch_bounds__(256) void k2_local(const float* __restrict__ h,
                         const int* __restrict__ adj,
                         const float* __restrict__ a0, const float* __restrict__ a1,
                         const float* __restrict__ a2, const float* __restrict__ a3,
                         float* __restrict__ hcomb){
    __shared__ __align__(16) float Hd[L*132];   // row-major, pad 132 (bank spread + f4 align)
    __shared__ float Alr[L*66];                  // alpha row-major, pad 66
    __shared__ __align__(16) float a4s[D*4];
    int tid = threadIdx.x;
    int tx = tid & 15, ty = tid >> 4;
    int b = blockIdx.x;

    for (int t = tid; t < D; t += 256){
        a4s[t*4+0] = a0[t]; a4s[t*4+1] = a1[t]; a4s[t*4+2] = a2[t]; a4s[t*4+3] = a3[t];
    }
    for (int e = tid; e < L*D; e += 256){        // coalesced global, conflict-free LDS
        int i = e / D, d = e - i*D;
        Hd[i*132 + d] = h[(long)(b*L+i)*D + d];
    }
    for (int e = tid; e < L*32; e += 256){       // zero pad cols [100,132)
        int i = e >> 5, c = D + (e & 31);
        Hd[i*132 + c] = 0.f;
    }
    __syncthreads();

    int ksel[4][4];
    #pragma unroll
    for (int i=0;i<4;++i)
        #pragma unroll
        for (int j=0;j<4;++j)
            ksel[i][j] = adj[((long)b*L + ty*4+i)*L + tx*4+j];

    float e0[4][4]={}, e1[4][4]={}, e2[4][4]={}, e3[4][4]={};
    for (int d = 0; d < D; ++d){
        float4 aw = *(const float4*)&a4s[d*4];
        float hi[4], hj[4];
        #pragma unroll
        for (int i=0;i<4;++i) hi[i] = Hd[(ty*4+i)*132 + d];
        #pragma unroll
        for (int j=0;j<4;++j) hj[j] = Hd[(tx*4+j)*132 + d];
        #pragma unroll
        for (int i=0;i<4;++i)
            #pragma unroll
            for (int j=0;j<4;++j){
                float p = hi[i]*hj[j];
                e0[i][j] += p*aw.x;
                e1[i][j] += p*aw.y;
                e2[i][j] += p*aw.z;
                e3[i][j] += p*aw.w;
            }
    }

    // masked row softmax (rows ty*4+i, cols across 16 tx lanes x 4)
    #pragma unroll
    for (int i=0;i<4;++i){
        float s[4];
        #pragma unroll
        for (int j=0;j<4;++j){
            int k = ksel[i][j];
            float ev = (k==1) ? e0[i][j] : (k==2) ? e1[i][j]
                     : (k==3) ? e2[i][j] : e3[i][j];
            s[j] = (k>=1 && k<=4) ? lrelu(ev) : NEG;
        }
        float m = fmaxf(fmaxf(s[0],s[1]), fmaxf(s[2],s[3]));
        #pragma unroll
        for (int off=1; off<16; off<<=1) m = fmaxf(m, __shfl_xor(m, off));
        float es[4], sum = 0.f;
        #pragma unroll
        for (int j=0;j<4;++j){ es[j] = expf(s[j]-m); sum += es[j]; }
        #pragma unroll
        for (int off=1; off<16; off<<=1) sum += __shfl_xor(sum, off);
        float inv = 1.f/sum;                      // all-NEG row -> uniform 1/64 (matches jax)
        #pragma unroll
        for (int j=0;j<4;++j) Alr[(ty*4+i)*66 + tx*4+j] = es[j]*inv;
    }
    __syncthreads();

    // phase 3: h_local[i][d] = sum_j alpha[i][j] * h[j][d]
    float o[4][8];
    #pragma unroll
    for (int i=0;i<4;++i)
        #pragma unroll
        for (int jj=0;jj<8;++jj) o[i][jj] = 0.f;
    for (int j = 0; j < L; ++j){
        float al[4];
        #pragma unroll
        for (int i=0;i<4;++i) al[i] = Alr[(ty*4+i)*66 + j];
        float4 b0 = *(const float4*)&Hd[j*132 + tx*4];
        float4 b1 = *(const float4*)&Hd[j*132 + 64 + tx*4];
        float bv[8] = {b0.x,b0.y,b0.z,b0.w,b1.x,b1.y,b1.z,b1.w};
        #pragma unroll
        for (int i=0;i<4;++i)
            #pragma unroll
            for (int jj=0;jj<8;++jj) o[i][jj] += al[i]*bv[jj];
    }
    #pragma unroll
    for (int i=0;i<4;++i){
        int row = ty*4+i;
        #pragma unroll
        for (int jj=0;jj<8;++jj){
            int d = (jj<4) ? (tx*4+jj) : (64 + tx*4 + (jj-4));
            if (d < D) hcomb[(long)(b*L+row)*D + d] = o[i][jj];   // h_local; k3c adds
        }
    }
}

// ---------------- K3a: att logits. GEMM M=196608 K=104 N=128(pad), fused lrelu+gw2 reduce ----
__global__ __launch_bounds__(256) void k3a_logits(const float* __restrict__ emb,
                          const float* __restrict__ sess,
                          const int* __restrict__ items, const int* __restrict__ adj_all,
                          const float* __restrict__ num_w,
                          const float* __restrict__ gw1, const float* __restrict__ gw2,
                          float* __restrict__ att_l){
    __shared__ __align__(16) float As[52*64];
    __shared__ __align__(16) float Bs[52*128];
    __shared__ float ss[104];
    __shared__ int   idxr[64];
    __shared__ float nbwr[64];
    __shared__ float gw2l[128];
    int tid = threadIdx.x;
    int tx = tid & 15, ty = tid >> 4;
    int r0 = blockIdx.x * 64;
    int b  = r0 / (L*S);

    if (tid < 64){
        int r = r0 + tid;
        int bl = r / S, s = r - bl*S;
        int it = items[bl];
        idxr[tid] = adj_all[it*S + s];
        nbwr[tid] = num_w[it*S + s];
    }
    if (tid < 104) ss[tid] = (tid < D) ? sess[b*D + tid] : 0.f;
    if (tid < 128) gw2l[tid] = (tid < D) ? gw2[tid] : 0.f;
    __syncthreads();

    float acc[4][8];
    #pragma unroll
    for (int i=0;i<4;++i)
        #pragma unroll
        for (int j=0;j<8;++j) acc[i][j] = 0.f;

    for (int chunk = 0; chunk < 2; ++chunk){
        int c0 = chunk*52;
        for (int e = tid; e < 64*13; e += 256){
            int rl = e & 63, cq = e >> 6;
            int cb = c0 + cq*4;
            float vx=0.f, vy=0.f, vz=0.f, vw=0.f;
            if (cb < D){
                const float4 v = *(const float4*)&emb[(long)idxr[rl]*D + cb];
                vx = v.x*ss[cb]; vy = v.y*ss[cb+1]; vz = v.z*ss[cb+2]; vw = v.w*ss[cb+3];
            } else if (cb == D){
                vx = nbwr[rl];
            }
            As[(cq*4+0)*64 + rl] = vx;
            As[(cq*4+1)*64 + rl] = vy;
            As[(cq*4+2)*64 + rl] = vz;
            As[(cq*4+3)*64 + rl] = vw;
        }
        for (int e = tid; e < 52*128; e += 256){
            int d = e & 127, cc = e >> 7;
            int c = c0 + cc;
            Bs[cc*128 + d] = (c <= D && d < D) ? gw1[c*D + d] : 0.f;
        }
        __syncthreads();
        for (int k = 0; k < 52; ++k){
            float4 a  = *(const float4*)&As[k*64 + ty*4];
            float4 b0 = *(const float4*)&Bs[k*128 + tx*4];
            float4 b1 = *(const float4*)&Bs[k*128 + 64 + tx*4];
            float av[4] = {a.x,a.y,a.z,a.w};
            float bv[8] = {b0.x,b0.y,b0.z,b0.w,b1.x,b1.y,b1.z,b1.w};
            #pragma unroll
            for (int i=0;i<4;++i)
                #pragma unroll
                for (int j=0;j<8;++j) acc[i][j] += av[i]*bv[j];
        }
        __syncthreads();
    }
    float g[8];
    #pragma unroll
    for (int j=0;j<8;++j) g[j] = gw2l[(j<4) ? (tx*4+j) : (64 + tx*4 + (j-4))];
    #pragma unroll
    for (int i=0;i<4;++i){
        float p = 0.f;
        #pragma unroll
        for (int j=0;j<8;++j) p += lrelu(acc[i][j]) * g[j];
        #pragma unroll
        for (int off=1; off<16; off<<=1) p += __shfl_xor(p, off);
        if (tx == 0) att_l[r0 + ty*4 + i] = p;
    }
}

// ---------------- K3b: softmax(12) + agg[bl][d] = sum_s att*nbr ----------------
__global__ __launch_bounds__(256) void k3b_agg(const float* __restrict__ emb,
                          const int* __restrict__ items, const int* __restrict__ adj_all,
                          const float* __restrict__ att_l,
                          float* __restrict__ agg){
    int p = blockIdx.x*2 + (threadIdx.x >> 7);   // bl index
    int t = threadIdx.x & 127;
    float lg[S];
    float m = -INFINITY;
    #pragma unroll
    for (int s=0;s<S;++s){ lg[s] = att_l[p*S + s]; m = fmaxf(m, lg[s]); }
    float sum = 0.f;
    #pragma unroll
    for (int s=0;s<S;++s){ lg[s] = expf(lg[s]-m); sum += lg[s]; }
    float inv = 1.f/sum;
    if (t < D){
        int it = items[p];
        float acc = 0.f;
        #pragma unroll
        for (int s=0;s<S;++s){
            int idx = adj_all[it*S + s];
            acc += lg[s]*inv * emb[(long)idx*D + t];
        }
        agg[p*D + t] = acc;
    }
}

// ---------------- K3c: hcomb += relu([h|agg] @ gw3). M=16384 K=208(pad) N=128(pad) ---------
__global__ __launch_bounds__(256) void k3c_hg(const float* __restrict__ h,
                          const float* __restrict__ agg, const float* __restrict__ gw3,
                          float* __restrict__ hcomb){
    __shared__ __align__(16) float As[52*64];
    __shared__ __align__(16) float Bs[52*128];
    int tid = threadIdx.x;
    int tx = tid & 15, ty = tid >> 4;
    int r0 = blockIdx.x * 64;

    float acc[4][8];
    #pragma unroll
    for (int i=0;i<4;++i)
        #pragma unroll
        for (int j=0;j<8;++j) acc[i][j] = 0.f;

    for (int chunk = 0; chunk < 4; ++chunk){
        int c0 = chunk*52;
        for (int e = tid; e < 64*13; e += 256){
            int rl = e & 63, cq = e >> 6;
            int cb = c0 + cq*4;
            float4 v = {0.f,0.f,0.f,0.f};
            if (cb < D)            v = *(const float4*)&h[(long)(r0+rl)*D + cb];
            else if (cb < 2*D)     v = *(const float4*)&agg[(long)(r0+rl)*D + (cb-D)];
            As[(cq*4+0)*64 + rl] = v.x;
            As[(cq*4+1)*64 + rl] = v.y;
            As[(cq*4+2)*64 + rl] = v.z;
            As[(cq*4+3)*64 + rl] = v.w;
        }
        for (int e = tid; e < 52*128; e += 256){
            int d = e & 127, cc = e >> 7;
            int c = c0 + cc;
            Bs[cc*128 + d] = (c < 2*D && d < D) ? gw3[c*D + d] : 0.f;
        }
        __syncthreads();
        for (int k = 0; k < 52; ++k){
            float4 a  = *(const float4*)&As[k*64 + ty*4];
            float4 b0 = *(const float4*)&Bs[k*128 + tx*4];
            float4 b1 = *(const float4*)&Bs[k*128 + 64 + tx*4];
            float av[4] = {a.x,a.y,a.z,a.w};
            float bv[8] = {b0.x,b0.y,b0.z,b0.w,b1.x,b1.y,b1.z,b1.w};
            #pragma unroll
            for (int i=0;i<4;++i)
                #pragma unroll
                for (int j=0;j<8;++j) acc[i][j] += av[i]*bv[j];
        }
        __syncthreads();
    }
    #pragma unroll
    for (int i=0;i<4;++i){
        int r = r0 + ty*4 + i;
        #pragma unroll
        for (int j=0;j<8;++j){
            int d = (j<4) ? (tx*4+j) : (64 + tx*4 + (j-4));
            if (d < D){
                long o = (long)r*D + d;
                hcomb[o] += fmaxf(acc[i][j], 0.f);
            }
        }
    }
}

// ---------------- K4a: per-b hs + gate. gate[b][d] = glu2_b[d] + sum_c hs[c]*glu2_w[c][d] ----
__global__ __launch_bounds__(128) void k4a_gate(const float* __restrict__ hcomb,
                          const int* __restrict__ alias_in, const float* __restrict__ mask,
                          const float* __restrict__ glu2_w, const float* __restrict__ glu2_b,
                          float* __restrict__ gate){
    int b = blockIdx.x; int tid = threadIdx.x;
    __shared__ float hsl[D];
    __shared__ float mkl[L];
    __shared__ int   al[L];
    if (tid < L){ al[tid] = alias_in[b*L+tid]; mkl[tid] = mask[b*L+tid]; }
    __syncthreads();
    if (tid < D){
        float acc = 0.f, msum = 0.f;
        for (int l = 0; l < L; ++l){
            acc  += hcomb[(long)(b*L + al[l])*D + tid] * mkl[l];
            msum += mkl[l];
        }
        hsl[tid] = acc / msum;
    }
    __syncthreads();
    if (tid < D){
        float g = glu2_b[tid];
        for (int c = 0; c < D; ++c) g += hsl[c]*glu2_w[c*D+tid];
        gate[b*D+tid] = g;
    }
}

// ---------------- K4b: nh1 = tanh(seqh @ w1[D:] + pos_part[l]). M=16384 K=100 N=128(pad) ----
__global__ __launch_bounds__(256) void k4b_nh1(const float* __restrict__ hcomb,
                          const int* __restrict__ alias_in,
                          const float* __restrict__ w1, const float* __restrict__ pos_part,
                          float* __restrict__ nh1){
    __shared__ __align__(16) float As[52*64];
    __shared__ __align__(16) float Bs[52*128];
    __shared__ int al[64];
    int tid = threadIdx.x;
    int tx = tid & 15, ty = tid >> 4;
    int b = blockIdx.x;            // tile == one b (64 rows)
    int r0 = b * 64;

    if (tid < 64) al[tid] = alias_in[r0 + tid];
    __syncthreads();

    float acc[4][8];
    #pragma unroll
    for (int i=0;i<4;++i)
        #pragma unroll
        for (int j=0;j<8;++j) acc[i][j] = 0.f;

    for (int chunk = 0; chunk < 2; ++chunk){
        int c0 = chunk*52;
        for (int e = tid; e < 64*13; e += 256){
            int rl = e & 63, cq = e >> 6;
            int cb = c0 + cq*4;
            float4 v = {0.f,0.f,0.f,0.f};
            if (cb < D) v = *(const float4*)&hcomb[(long)(r0 + al[rl])*D + cb];
            As[(cq*4+0)*64 + rl] = v.x;
            As[(cq*4+1)*64 + rl] = v.y;
            As[(cq*4+2)*64 + rl] = v.z;
            As[(cq*4+3)*64 + rl] = v.w;
        }
        for (int e = tid; e < 52*128; e += 256){
            int d = e & 127, cc = e >> 7;
            int c = c0 + cc;
            Bs[cc*128 + d] = (c < D && d < D) ? w1[(D+c)*D + d] : 0.f;
        }
        __syncthreads();
        for (int k = 0; k < 52; ++k){
            float4 a  = *(const float4*)&As[k*64 + ty*4];
            float4 b0 = *(const float4*)&Bs[k*128 + tx*4];
            float4 b1 = *(const float4*)&Bs[k*128 + 64 + tx*4];
            float av[4] = {a.x,a.y,a.z,a.w};
            float bv[8] = {b0.x,b0.y,b0.z,b0.w,b1.x,b1.y,b1.z,b1.w};
            #pragma unroll
            for (int i=0;i<4;++i)
                #pragma unroll
                for (int j=0;j<8;++j) acc[i][j] += av[i]*bv[j];
        }
        __syncthreads();
    }
    #pragma unroll
    for (int i=0;i<4;++i){
        int rl = ty*4 + i;              // == l
        #pragma unroll
        for (int j=0;j<8;++j){
            int d = (j<4) ? (tx*4+j) : (64 + tx*4 + (j-4));
            if (d < D){
                float v = tanhf(acc[i][j] + pos_part[rl*D + d]);
                nh1[(long)(r0+rl)*D + d] = v;
            }
        }
    }
}

// ---------------- K4c: nh2=sigmoid(nh1@glu1+gate); beta=(nh2.w2)*mask; select=sum beta*seqh --
__global__ __launch_bounds__(256) void k4c_select(const float* __restrict__ nh1,
                          const float* __restrict__ hcomb, const int* __restrict__ alias_in,
                          const float* __restrict__ glu1_w, const float* __restrict__ gate,
                          const float* __restrict__ w2, const float* __restrict__ mask,
                          float* __restrict__ sel_out){
    __shared__ __align__(16) float As[104*64];   // nh1 k-major, full K
    __shared__ __align__(16) float Bs[52*128];
    __shared__ __align__(16) float Ss[64*D];     // seqh rows (row-major)
    __shared__ float red[16*128];
    __shared__ float w2l[128];
    __shared__ float mkl[64];
    __shared__ int   al[64];
    int tid = threadIdx.x;
    int tx = tid & 15, ty = tid >> 4;
    int b = blockIdx.x;
    int r0 = b * 64;

    if (tid < 64){ al[tid] = alias_in[r0 + tid]; mkl[tid] = mask[r0 + tid]; }
    if (tid < 128) w2l[tid] = (tid < D) ? w2[tid] : 0.f;
    __syncthreads();

    for (int e = tid; e < 64*26; e += 256){
        int rl = e & 63, cq = e >> 6;
        int cb = cq*4;
        float4 v = {0.f,0.f,0.f,0.f};
        if (cb < D) v = *(const float4*)&nh1[(long)(r0+rl)*D + cb];
        As[(cb+0)*64 + rl] = v.x;
        As[(cb+1)*64 + rl] = v.y;
        As[(cb+2)*64 + rl] = v.z;
        As[(cb+3)*64 + rl] = v.w;
    }
    for (int e = tid; e < 64*25; e += 256){
        int rl = e / 25, q = e % 25;
        *(float4*)&Ss[rl*D + q*4] = *(const float4*)&hcomb[(long)(r0 + al[rl])*D + q*4];
    }

    float acc[4][8];
    #pragma unroll
    for (int i=0;i<4;++i)
        #pragma unroll
        for (int j=0;j<8;++j) acc[i][j] = 0.f;

    for (int chunk = 0; chunk < 2; ++chunk){
        int c0 = chunk*52;
        __syncthreads();
        for (int e = tid; e < 52*128; e += 256){
            int d = e & 127, cc = e >> 7;
            int c = c0 + cc;
            Bs[cc*128 + d] = (c < D && d < D) ? glu1_w[c*D + d] : 0.f;
        }
        __syncthreads();
        for (int k = 0; k < 52; ++k){
            float4 a  = *(const float4*)&As[(c0+k)*64 + ty*4];
            float4 b0 = *(const float4*)&Bs[k*128 + tx*4];
            float4 b1 = *(const float4*)&Bs[k*128 + 64 + tx*4];
            float av[4] = {a.x,a.y,a.z,a.w};
            float bv[8] = {b0.x,b0.y,b0.z,b0.w,b1.x,b1.y,b1.z,b1.w};
            #pragma unroll
            for (int i=0;i<4;++i)
                #pragma unroll
                for (int j=0;j<8;++j) acc[i][j] += av[i]*bv[j];
        }
    }
    __syncthreads();

    float gl[8];
    #pragma unroll
    for (int j=0;j<8;++j){
        int d = (j<4) ? (tx*4+j) : (64 + tx*4 + (j-4));
        gl[j] = (d < D) ? gate[b*D + d] : 0.f;
    }
    float sp[8];
    #pragma unroll
    for (int j=0;j<8;++j) sp[j] = 0.f;
    #pragma unroll
    for (int i=0;i<4;++i){
        int rl = ty*4 + i;
        float p = 0.f;
        #pragma unroll
        for (int j=0;j<8;++j){
            int d = (j<4) ? (tx*4+j) : (64 + tx*4 + (j-4));
            float z = acc[i][j] + gl[j];
            float nh2 = 1.f/(1.f+expf(-z));
            p += nh2 * w2l[d];
        }
        #pragma unroll
        for (int off=1; off<16; off<<=1) p += __shfl_xor(p, off);   // all 16 lanes get sum
        float beta = p * mkl[rl];
        #pragma unroll
        for (int j=0;j<8;++j){
            int d = (j<4) ? (tx*4+j) : (64 + tx*4 + (j-4));
            if (d < D) sp[j] += beta * Ss[rl*D + d];
        }
    }
    #pragma unroll
    for (int j=0;j<8;++j){
        int d = (j<4) ? (tx*4+j) : (64 + tx*4 + (j-4));
        red[ty*128 + d] = sp[j];
    }
    __syncthreads();
    if (tid < 128){
        float s = 0.f;
        #pragma unroll
        for (int g=0; g<16; ++g) s += red[g*128 + tid];
        if (tid < D) sel_out[b*D + tid] = s;
    }
}

// ---------------- K5: score tile GEMM + fused per-row online softmax stats ----------------
__global__ __launch_bounds__(256) void k5_score(const float* __restrict__ emb,
                                                const float* __restrict__ sel,
                                                float* __restrict__ out,
                                                float* __restrict__ pstats){
    __shared__ __align__(16) float As[52*64];
    __shared__ __align__(16) float Bs[52*128];
    int tid = threadIdx.x;
    int tx = tid & 15, ty = tid >> 4;
    int n0 = blockIdx.x * 128;
    int m0 = blockIdx.y * 64;

    float acc[4][8];
    #pragma unroll
    for (int i=0;i<4;++i)
        #pragma unroll
        for (int j=0;j<8;++j) acc[i][j] = 0.f;

    for (int chunk = 0; chunk < 2; ++chunk){
        int c0 = chunk*52;
        for (int e = tid; e < 64*13; e += 256){
            int rl = e & 63, cq = e >> 6;
            int cb = c0 + cq*4;
            float4 v = {0.f,0.f,0.f,0.f};
            if (cb < D) v = *(const float4*)&sel[(long)(m0+rl)*D + cb];
            As[(cq*4+0)*64 + rl] = v.x;
            As[(cq*4+1)*64 + rl] = v.y;
            As[(cq*4+2)*64 + rl] = v.z;
            As[(cq*4+3)*64 + rl] = v.w;
        }
        for (int e = tid; e < 128*13; e += 256){
            int nl = e & 127, cq = e >> 7;
            int cb = c0 + cq*4;
            int n = n0 + nl;
            float4 v = {0.f,0.f,0.f,0.f};
            if (cb < D && n < E) v = *(const float4*)&emb[(long)(1+n)*D + cb];
            Bs[(cq*4+0)*128 + nl] = v.x;
            Bs[(cq*4+1)*128 + nl] = v.y;
            Bs[(cq*4+2)*128 + nl] = v.z;
            Bs[(cq*4+3)*128 + nl] = v.w;
        }
        __syncthreads();
        for (int k = 0; k < 52; ++k){
            float4 a  = *(const float4*)&As[k*64 + ty*4];
            float4 b0 = *(const float4*)&Bs[k*128 + tx*4];
            float4 b1 = *(const float4*)&Bs[k*128 + 64 + tx*4];
            float av[4] = {a.x,a.y,a.z,a.w};
            float bv[8] = {b0.x,b0.y,b0.z,b0.w,b1.x,b1.y,b1.z,b1.w};
            #pragma unroll
            for (int i=0;i<4;++i)
                #pragma unroll
                for (int j=0;j<8;++j) acc[i][j] += av[i]*bv[j];
        }
        __syncthreads();
    }
    bool fullTile = (n0 + 128 <= E);
    #pragma unroll
    for (int i=0;i<4;++i){
        int m = m0 + ty*4 + i;
        long rowo = (long)m*E;
        if (fullTile){
            *(float4*)&out[rowo + n0 + tx*4]      = *(float4*)&acc[i][0];
            *(float4*)&out[rowo + n0 + 64 + tx*4] = *(float4*)&acc[i][4];
        } else {
            #pragma unroll
            for (int j=0;j<8;++j){
                int n = n0 + ((j<4) ? (tx*4+j) : (64 + tx*4 + (j-4)));
                if (n < E) out[rowo + n] = acc[i][j];
            }
        }
        float mx = -INFINITY, sm = 0.f;
        #pragma unroll
        for (int j=0;j<8;++j){
            int n = n0 + ((j<4) ? (tx*4+j) : (64 + tx*4 + (j-4)));
            if (n < E){
                float v = acc[i][j];
                if (v > mx){ sm = sm*expf(mx - v) + 1.f; mx = v; }
                else         sm += expf(v - mx);
            }
        }
        #pragma unroll
        for (int off=1; off<16; off<<=1){
            float mo = __shfl_xor(mx, off);
            float so = __shfl_xor(sm, off);
            float mm = fmaxf(mx, mo);
            float sn = 0.f;
            if (mx > -INFINITY) sn += sm*expf(mx-mm);
            if (mo > -INFINITY) sn += so*expf(mo-mm);
            mx = mm; sm = sn;
        }
        if (tx == 0){
            long o = ((long)m*NT5 + blockIdx.x)*2;
            pstats[o] = mx; pstats[o+1] = sm;
        }
    }
}

// ---------------- K7: combine per-row partial stats ----------------
__global__ __launch_bounds__(256) void k7_combine(const float* __restrict__ pstats,
                                                  float* __restrict__ MS){
    int row = blockIdx.x;
    int tid = threadIdx.x;
    float m = -INFINITY, s = 0.f;
    for (int t = tid; t < NT5; t += 256){
        long o = ((long)row*NT5 + t)*2;
        float m2 = pstats[o], s2 = pstats[o+1];
        float mm = fmaxf(m, m2);
        float sn = 0.f;
        if (m  > -INFINITY) sn += s *expf(m -mm);
        if (m2 > -INFINITY) sn += s2*expf(m2-mm);
        m = mm; s = sn;
    }
    __shared__ float ms[256], ss[256];
    ms[tid] = m; ss[tid] = s;
    __syncthreads();
    for (int off = 128; off >= 1; off >>= 1){
        if (tid < off){
            float m1 = ms[tid], s1 = ss[tid];
            float m2 = ms[tid+off], s2 = ss[tid+off];
            float mm = fmaxf(m1, m2);
            float sn = 0.f;
            if (m1 > -INFINITY) sn += s1*expf(m1-mm);
            if (m2 > -INFINITY) sn += s2*expf(m2-mm);
            ms[tid] = mm; ss[tid] = sn;
        }
        __syncthreads();
    }
    if (tid == 0){ MS[row*2] = ms[0]; MS[row*2+1] = 1.f/ss[0]; }
}

// ---------------- K8: normalize in place ----------------
__global__ __launch_bounds__(256) void k8_norm(float* __restrict__ out,
                                               const float* __restrict__ MS){
    int b = blockIdx.y;
    int n = blockIdx.x*256 + threadIdx.x;
    if (n < E){
        float m = MS[b*2], invs = MS[b*2+1];
        long i = (long)b*E + n;
        out[i] = expf(out[i] - m) * invs;
    }
}

extern "C" void kernel_launch(void* const* d_in, const int* in_sizes, int n_in,
                              void* d_out, int out_size, void* d_ws, size_t ws_size,
                              hipStream_t stream) {
    const float* emb       = (const float*)d_in[0];
    const float* pos_table = (const float*)d_in[1];
    const float* w1        = (const float*)d_in[2];
    const float* w2        = (const float*)d_in[3];
    const float* glu1_w    = (const float*)d_in[4];
    const float* glu2_w    = (const float*)d_in[5];
    const float* glu2_b    = (const float*)d_in[6];
    const float* a0        = (const float*)d_in[7];
    const float* a1        = (const float*)d_in[8];
    const float* a2        = (const float*)d_in[9];
    const float* a3        = (const float*)d_in[10];
    const float* gw1       = (const float*)d_in[11];
    const float* gw2       = (const float*)d_in[12];
    const float* gw3       = (const float*)d_in[13];
    const float* num_w     = (const float*)d_in[14];
    const float* mask      = (const float*)d_in[15];
    const int*   alias_in  = (const int*)d_in[16];
    const int*   adj       = (const int*)d_in[17];
    const int*   items     = (const int*)d_in[18];
    const int*   seqf      = (const int*)d_in[19];
    const int*   adj_all   = (const int*)d_in[20];

    float* ws       = (float*)d_ws;
    float* h        = ws;                       // B*L*D
    float* hcomb    = h + B*L*D;                // B*L*D
    float* sess     = hcomb + B*L*D;            // B*D
    float* pos_part = sess + B*D;               // L*D
    float* sel      = pos_part + L*D;           // B*D
    float* att_l    = sel + B*D;                // M3A
    float* agg      = att_l + M3A;              // B*L*D (reused as nh1 after k3c)
    float* pstats   = agg + B*L*D;              // B*NT5*2
    float* MS       = pstats + B*NT5*2;         // B*2
    float* gate     = MS + B*2;                 // B*D
    float* nh1      = agg;                      // reuse (agg dead after k3c)

    float* out = (float*)d_out;

    k0_pos    <<<dim3(L), dim3(128), 0, stream>>>(pos_table, w1, pos_part);
    k1_gather <<<dim3(B), dim3(128), 0, stream>>>(emb, items, seqf, mask, h, sess);
    k2_local  <<<dim3(B), dim3(256), 0, stream>>>(h, adj, a0, a1, a2, a3, hcomb);
    k3a_logits<<<dim3(M3A/64), dim3(256), 0, stream>>>(emb, sess, items, adj_all, num_w,
                                                       gw1, gw2, att_l);
    k3b_agg   <<<dim3(B*L/2), dim3(256), 0, stream>>>(emb, items, adj_all, att_l, agg);
    k3c_hg    <<<dim3(B*L/64), dim3(256), 0, stream>>>(h, agg, gw3, hcomb);
    k4a_gate  <<<dim3(B), dim3(128), 0, stream>>>(hcomb, alias_in, mask, glu2_w, glu2_b, gate);
    k4b_nh1   <<<dim3(B), dim3(256), 0, stream>>>(hcomb, alias_in, w1, pos_part, nh1);
    k4c_select<<<dim3(B), dim3(256), 0, stream>>>(nh1, hcomb, alias_in, glu1_w, gate,
                                                  w2, mask, sel);
    k5_score  <<<dim3(NT5, 4), dim3(256), 0, stream>>>(emb, sel, out, pstats);
    k7_combine<<<dim3(B), dim3(256), 0, stream>>>(pstats, MS);
    k8_norm   <<<dim3((E + 255)/256, B), dim3(256), 0, stream>>>(out, MS);
}

// Round 9
// 642.791 us; speedup vs baseline: 1.6545x; 1.0360x over previous
//
#include <hip/hip_runtime.h>
#include <math.h>

#define B 256
#define L 64
#define D 100
#define S 12
#define NN 100000
#define E 99999
#define NEG -9e15f
#define LRELU 0.2f
#define M3A (B*L*S)          // 196608 rows for k3a
#define NT5 782              // ceil(E/128) col tiles in k5

__device__ __forceinline__ float lrelu(float x){ return x > 0.f ? x : LRELU*x; }

// ---------------- K0: pos_part[l][d] = sum_c pos[l][c]*w1[c][d] ----------------
__global__ void k0_pos(const float* __restrict__ pos, const float* __restrict__ w1,
                       float* __restrict__ pos_part){
    int l = blockIdx.x; int d = threadIdx.x;
    if (d >= D) return;
    float acc = 0.f;
    for (int c = 0; c < D; ++c) acc += pos[l*D+c] * w1[c*D+d];
    pos_part[l*D+d] = acc;
}

// ---------------- K1: h = emb[items]; sess = masked mean of emb[seq_features] ----------------
__global__ void k1_gather(const float* __restrict__ emb, const int* __restrict__ items,
                          const int* __restrict__ seqf, const float* __restrict__ mask,
                          float* __restrict__ h, float* __restrict__ sess){
    int b = blockIdx.x; int tid = threadIdx.x;
    // h copy vectorized: 64 rows x 25 float4 (emb rows are 400B -> 16B aligned)
    for (int e = tid; e < L*25; e += blockDim.x){
        int l = e / 25, q = e % 25;
        *(float4*)&h[(long)(b*L+l)*D + q*4] =
            *(const float4*)&emb[(long)items[b*L+l]*D + q*4];
    }
    if (tid < D){
        float acc = 0.f, msum = 0.f;
        for (int l = 0; l < L; ++l){
            float mk = mask[b*L+l];
            acc  += emb[(long)seqf[b*L+l]*D + tid] * mk;
            msum += mk;
        }
        sess[b*D+tid] = acc / msum;
    }
}

// ---------------- K2: local aggregator, one block per b ----------------
__global__ __launch_bounds__(256) void k2_local(const float* __restrict__ h,
                         const int* __restrict__ adj,
                         const float* __restrict__ a0, const float* __restrict__ a1,
                         const float* __restrict__ a2, const float* __restrict__ a3,
                         float* __restrict__ hcomb){
    __shared__ __align__(16) float Hd[L*132];
    __shared__ float Alr[L*66];
    __shared__ __align__(16) float a4s[D*4];
    int tid = threadIdx.x;
    int tx = tid & 15, ty = tid >> 4;
    int b = blockIdx.x;

    for (int t = tid; t < D; t += 256){
        a4s[t*4+0] = a0[t]; a4s[t*4+1] = a1[t]; a4s[t*4+2] = a2[t]; a4s[t*4+3] = a3[t];
    }
    for (int e = tid; e < L*D; e += 256){
        int i = e / D, d = e - i*D;
        Hd[i*132 + d] = h[(long)(b*L+i)*D + d];
    }
    for (int e = tid; e < L*32; e += 256){
        int i = e >> 5, c = D + (e & 31);
        Hd[i*132 + c] = 0.f;
    }
    __syncthreads();

    int ksel[4][4];
    #pragma unroll
    for (int i=0;i<4;++i)
        #pragma unroll
        for (int j=0;j<4;++j)
            ksel[i][j] = adj[((long)b*L + ty*4+i)*L + tx*4+j];

    float e0[4][4]={}, e1[4][4]={}, e2[4][4]={}, e3[4][4]={};
    for (int d = 0; d < D; ++d){
        float4 aw = *(const float4*)&a4s[d*4];
        float hi[4], hj[4];
        #pragma unroll
        for (int i=0;i<4;++i) hi[i] = Hd[(ty*4+i)*132 + d];
        #pragma unroll
        for (int j=0;j<4;++j) hj[j] = Hd[(tx*4+j)*132 + d];
        #pragma unroll
        for (int i=0;i<4;++i)
            #pragma unroll
            for (int j=0;j<4;++j){
                float p = hi[i]*hj[j];
                e0[i][j] += p*aw.x;
                e1[i][j] += p*aw.y;
                e2[i][j] += p*aw.z;
                e3[i][j] += p*aw.w;
            }
    }

    #pragma unroll
    for (int i=0;i<4;++i){
        float s[4];
        #pragma unroll
        for (int j=0;j<4;++j){
            int k = ksel[i][j];
            float ev = (k==1) ? e0[i][j] : (k==2) ? e1[i][j]
                     : (k==3) ? e2[i][j] : e3[i][j];
            s[j] = (k>=1 && k<=4) ? lrelu(ev) : NEG;
        }
        float m = fmaxf(fmaxf(s[0],s[1]), fmaxf(s[2],s[3]));
        #pragma unroll
        for (int off=1; off<16; off<<=1) m = fmaxf(m, __shfl_xor(m, off));
        float es[4], sum = 0.f;
        #pragma unroll
        for (int j=0;j<4;++j){ es[j] = expf(s[j]-m); sum += es[j]; }
        #pragma unroll
        for (int off=1; off<16; off<<=1) sum += __shfl_xor(sum, off);
        float inv = 1.f/sum;
        #pragma unroll
        for (int j=0;j<4;++j) Alr[(ty*4+i)*66 + tx*4+j] = es[j]*inv;
    }
    __syncthreads();

    float o[4][8];
    #pragma unroll
    for (int i=0;i<4;++i)
        #pragma unroll
        for (int jj=0;jj<8;++jj) o[i][jj] = 0.f;
    for (int j = 0; j < L; ++j){
        float al[4];
        #pragma unroll
        for (int i=0;i<4;++i) al[i] = Alr[(ty*4+i)*66 + j];
        float4 b0 = *(const float4*)&Hd[j*132 + tx*4];
        float4 b1 = *(const float4*)&Hd[j*132 + 64 + tx*4];
        float bv[8] = {b0.x,b0.y,b0.z,b0.w,b1.x,b1.y,b1.z,b1.w};
        #pragma unroll
        for (int i=0;i<4;++i)
            #pragma unroll
            for (int jj=0;jj<8;++jj) o[i][jj] += al[i]*bv[jj];
    }
    #pragma unroll
    for (int i=0;i<4;++i){
        int row = ty*4+i;
        #pragma unroll
        for (int jj=0;jj<8;++jj){
            int d = (jj<4) ? (tx*4+jj) : (64 + tx*4 + (jj-4));
            if (d < D) hcomb[(long)(b*L+row)*D + d] = o[i][jj];
        }
    }
}

// ---------------- K3a: att logits. 128-row x 128(pad)-col tiles, 8x8/thread ----------------
// row r = bl*S + s; 128 | 768 so each block is within one b. No extra LDS beyond As/Bs.
__global__ __launch_bounds__(256) void k3a_logits(const float* __restrict__ emb,
                          const float* __restrict__ sess,
                          const int* __restrict__ items, const int* __restrict__ adj_all,
                          const float* __restrict__ num_w,
                          const float* __restrict__ gw1, const float* __restrict__ gw2,
                          float* __restrict__ att_l){
    __shared__ __align__(16) float As[52*128];
    __shared__ __align__(16) float Bs[52*128];
    int tid = threadIdx.x;
    int tx = tid & 15, ty = tid >> 4;
    int r0 = blockIdx.x * 128;
    int b  = r0 / (L*S);

    float acc[8][8];
    #pragma unroll
    for (int i=0;i<8;++i)
        #pragma unroll
        for (int j=0;j<8;++j) acc[i][j] = 0.f;

    for (int chunk = 0; chunk < 2; ++chunk){
        int c0 = chunk*52;
        // stage A (k-major): ain[r0+rl][cb..cb+3]
        for (int e = tid; e < 128*13; e += 256){
            int rl = e & 127, cq = e >> 7;
            int cb = c0 + cq*4;
            int r = r0 + rl;
            int bl = r / S, s = r - bl*S;
            int it = items[bl];
            float vx=0.f, vy=0.f, vz=0.f, vw=0.f;
            if (cb < D){
                int idx = adj_all[it*S + s];
                const float4 v  = *(const float4*)&emb[(long)idx*D + cb];
                const float4 sv = *(const float4*)&sess[(long)b*D + cb];
                vx = v.x*sv.x; vy = v.y*sv.y; vz = v.z*sv.z; vw = v.w*sv.w;
            } else if (cb == D){
                vx = num_w[it*S + s];
            }
            As[(cq*4+0)*128 + rl] = vx;
            As[(cq*4+1)*128 + rl] = vy;
            As[(cq*4+2)*128 + rl] = vz;
            As[(cq*4+3)*128 + rl] = vw;
        }
        // stage B: Bs[cc][d] = gw1[c0+cc][d]
        for (int e = tid; e < 52*128; e += 256){
            int d = e & 127, cc = e >> 7;
            int c = c0 + cc;
            Bs[cc*128 + d] = (c <= D && d < D) ? gw1[c*D + d] : 0.f;
        }
        __syncthreads();
        for (int k = 0; k < 52; ++k){
            float4 a0v = *(const float4*)&As[k*128 + ty*8];
            float4 a1v = *(const float4*)&As[k*128 + ty*8 + 4];
            float4 b0 = *(const float4*)&Bs[k*128 + tx*4];
            float4 b1 = *(const float4*)&Bs[k*128 + 64 + tx*4];
            float av[8] = {a0v.x,a0v.y,a0v.z,a0v.w,a1v.x,a1v.y,a1v.z,a1v.w};
            float bv[8] = {b0.x,b0.y,b0.z,b0.w,b1.x,b1.y,b1.z,b1.w};
            #pragma unroll
            for (int i=0;i<8;++i)
                #pragma unroll
                for (int j=0;j<8;++j) acc[i][j] += av[i]*bv[j];
        }
        __syncthreads();
    }
    // epilogue: logit = sum_d lrelu(t1)*gw2[d], reduce over tx lanes
    float g[8];
    #pragma unroll
    for (int j=0;j<8;++j){
        int d = (j<4) ? (tx*4+j) : (64 + tx*4 + (j-4));
        g[j] = (d < D) ? gw2[d] : 0.f;
    }
    #pragma unroll
    for (int i=0;i<8;++i){
        float p = 0.f;
        #pragma unroll
        for (int j=0;j<8;++j) p += lrelu(acc[i][j]) * g[j];
        #pragma unroll
        for (int off=1; off<16; off<<=1) p += __shfl_xor(p, off);
        if (tx == 0) att_l[r0 + ty*8 + i] = p;
    }
}

// ---------------- K3b: softmax(12) + agg[bl][d] = sum_s att*nbr ----------------
__global__ __launch_bounds__(256) void k3b_agg(const float* __restrict__ emb,
                          const int* __restrict__ items, const int* __restrict__ adj_all,
                          const float* __restrict__ att_l,
                          float* __restrict__ agg){
    int p = blockIdx.x*2 + (threadIdx.x >> 7);   // bl index
    int t = threadIdx.x & 127;
    float lg[S];
    float m = -INFINITY;
    #pragma unroll
    for (int s=0;s<S;++s){ lg[s] = att_l[p*S + s]; m = fmaxf(m, lg[s]); }
    float sum = 0.f;
    #pragma unroll
    for (int s=0;s<S;++s){ lg[s] = expf(lg[s]-m); sum += lg[s]; }
    float inv = 1.f/sum;
    if (t < D){
        int it = items[p];
        float acc = 0.f;
        #pragma unroll
        for (int s=0;s<S;++s){
            int idx = adj_all[it*S + s];
            acc += lg[s]*inv * emb[(long)idx*D + t];
        }
        agg[p*D + t] = acc;
    }
}

// ---------------- K3c: hcomb += relu([h|agg] @ gw3). M=16384 K=208(pad) N=128(pad) ---------
__global__ __launch_bounds__(256) void k3c_hg(const float* __restrict__ h,
                          const float* __restrict__ agg, const float* __restrict__ gw3,
                          float* __restrict__ hcomb){
    __shared__ __align__(16) float As[52*64];
    __shared__ __align__(16) float Bs[52*128];
    int tid = threadIdx.x;
    int tx = tid & 15, ty = tid >> 4;
    int r0 = blockIdx.x * 64;

    float acc[4][8];
    #pragma unroll
    for (int i=0;i<4;++i)
        #pragma unroll
        for (int j=0;j<8;++j) acc[i][j] = 0.f;

    for (int chunk = 0; chunk < 4; ++chunk){
        int c0 = chunk*52;
        for (int e = tid; e < 64*13; e += 256){
            int rl = e & 63, cq = e >> 6;
            int cb = c0 + cq*4;
            float4 v = {0.f,0.f,0.f,0.f};
            if (cb < D)            v = *(const float4*)&h[(long)(r0+rl)*D + cb];
            else if (cb < 2*D)     v = *(const float4*)&agg[(long)(r0+rl)*D + (cb-D)];
            As[(cq*4+0)*64 + rl] = v.x;
            As[(cq*4+1)*64 + rl] = v.y;
            As[(cq*4+2)*64 + rl] = v.z;
            As[(cq*4+3)*64 + rl] = v.w;
        }
        for (int e = tid; e < 52*128; e += 256){
            int d = e & 127, cc = e >> 7;
            int c = c0 + cc;
            Bs[cc*128 + d] = (c < 2*D && d < D) ? gw3[c*D + d] : 0.f;
        }
        __syncthreads();
        for (int k = 0; k < 52; ++k){
            float4 a  = *(const float4*)&As[k*64 + ty*4];
            float4 b0 = *(const float4*)&Bs[k*128 + tx*4];
            float4 b1 = *(const float4*)&Bs[k*128 + 64 + tx*4];
            float av[4] = {a.x,a.y,a.z,a.w};
            float bv[8] = {b0.x,b0.y,b0.z,b0.w,b1.x,b1.y,b1.z,b1.w};
            #pragma unroll
            for (int i=0;i<4;++i)
                #pragma unroll
                for (int j=0;j<8;++j) acc[i][j] += av[i]*bv[j];
        }
        __syncthreads();
    }
    #pragma unroll
    for (int i=0;i<4;++i){
        int r = r0 + ty*4 + i;
        #pragma unroll
        for (int j=0;j<8;++j){
            int d = (j<4) ? (tx*4+j) : (64 + tx*4 + (j-4));
            if (d < D){
                long o = (long)r*D + d;
                hcomb[o] += fmaxf(acc[i][j], 0.f);
            }
        }
    }
}

// ---------------- K4a: per-b hs + gate ----------------
__global__ __launch_bounds__(128) void k4a_gate(const float* __restrict__ hcomb,
                          const int* __restrict__ alias_in, const float* __restrict__ mask,
                          const float* __restrict__ glu2_w, const float* __restrict__ glu2_b,
                          float* __restrict__ gate){
    int b = blockIdx.x; int tid = threadIdx.x;
    __shared__ float hsl[D];
    __shared__ float mkl[L];
    __shared__ int   al[L];
    if (tid < L){ al[tid] = alias_in[b*L+tid]; mkl[tid] = mask[b*L+tid]; }
    __syncthreads();
    if (tid < D){
        float acc = 0.f, msum = 0.f;
        for (int l = 0; l < L; ++l){
            acc  += hcomb[(long)(b*L + al[l])*D + tid] * mkl[l];
            msum += mkl[l];
        }
        hsl[tid] = acc / msum;
    }
    __syncthreads();
    if (tid < D){
        float g = glu2_b[tid];
        for (int c = 0; c < D; ++c) g += hsl[c]*glu2_w[c*D+tid];
        gate[b*D+tid] = g;
    }
}

// ---------------- K4b: nh1 = tanh(seqh @ w1[D:] + pos_part[l]) ----------------
__global__ __launch_bounds__(256) void k4b_nh1(const float* __restrict__ hcomb,
                          const int* __restrict__ alias_in,
                          const float* __restrict__ w1, const float* __restrict__ pos_part,
                          float* __restrict__ nh1){
    __shared__ __align__(16) float As[52*64];
    __shared__ __align__(16) float Bs[52*128];
    __shared__ int al[64];
    int tid = threadIdx.x;
    int tx = tid & 15, ty = tid >> 4;
    int b = blockIdx.x;
    int r0 = b * 64;

    if (tid < 64) al[tid] = alias_in[r0 + tid];
    __syncthreads();

    float acc[4][8];
    #pragma unroll
    for (int i=0;i<4;++i)
        #pragma unroll
        for (int j=0;j<8;++j) acc[i][j] = 0.f;

    for (int chunk = 0; chunk < 2; ++chunk){
        int c0 = chunk*52;
        for (int e = tid; e < 64*13; e += 256){
            int rl = e & 63, cq = e >> 6;
            int cb = c0 + cq*4;
            float4 v = {0.f,0.f,0.f,0.f};
            if (cb < D) v = *(const float4*)&hcomb[(long)(r0 + al[rl])*D + cb];
            As[(cq*4+0)*64 + rl] = v.x;
            As[(cq*4+1)*64 + rl] = v.y;
            As[(cq*4+2)*64 + rl] = v.z;
            As[(cq*4+3)*64 + rl] = v.w;
        }
        for (int e = tid; e < 52*128; e += 256){
            int d = e & 127, cc = e >> 7;
            int c = c0 + cc;
            Bs[cc*128 + d] = (c < D && d < D) ? w1[(D+c)*D + d] : 0.f;
        }
        __syncthreads();
        for (int k = 0; k < 52; ++k){
            float4 a  = *(const float4*)&As[k*64 + ty*4];
            float4 b0 = *(const float4*)&Bs[k*128 + tx*4];
            float4 b1 = *(const float4*)&Bs[k*128 + 64 + tx*4];
            float av[4] = {a.x,a.y,a.z,a.w};
            float bv[8] = {b0.x,b0.y,b0.z,b0.w,b1.x,b1.y,b1.z,b1.w};
            #pragma unroll
            for (int i=0;i<4;++i)
                #pragma unroll
                for (int j=0;j<8;++j) acc[i][j] += av[i]*bv[j];
        }
        __syncthreads();
    }
    #pragma unroll
    for (int i=0;i<4;++i){
        int rl = ty*4 + i;
        #pragma unroll
        for (int j=0;j<8;++j){
            int d = (j<4) ? (tx*4+j) : (64 + tx*4 + (j-4));
            if (d < D){
                float v = tanhf(acc[i][j] + pos_part[rl*D + d]);
                nh1[(long)(r0+rl)*D + d] = v;
            }
        }
    }
}

// ---------------- K4c: nh2=sigmoid(nh1@glu1+gate); beta=(nh2.w2)*mask; select=sum beta*seqh --
__global__ __launch_bounds__(256) void k4c_select(const float* __restrict__ nh1,
                          const float* __restrict__ hcomb, const int* __restrict__ alias_in,
                          const float* __restrict__ glu1_w, const float* __restrict__ gate,
                          const float* __restrict__ w2, const float* __restrict__ mask,
                          float* __restrict__ sel_out){
    __shared__ __align__(16) float As[104*64];
    __shared__ __align__(16) float Bs[52*128];
    __shared__ __align__(16) float Ss[64*D];
    __shared__ float red[16*128];
    __shared__ float w2l[128];
    __shared__ float mkl[64];
    __shared__ int   al[64];
    int tid = threadIdx.x;
    int tx = tid & 15, ty = tid >> 4;
    int b = blockIdx.x;
    int r0 = b * 64;

    if (tid < 64){ al[tid] = alias_in[r0 + tid]; mkl[tid] = mask[r0 + tid]; }
    if (tid < 128) w2l[tid] = (tid < D) ? w2[tid] : 0.f;
    __syncthreads();

    for (int e = tid; e < 64*26; e += 256){
        int rl = e & 63, cq = e >> 6;
        int cb = cq*4;
        float4 v = {0.f,0.f,0.f,0.f};
        if (cb < D) v = *(const float4*)&nh1[(long)(r0+rl)*D + cb];
        As[(cb+0)*64 + rl] = v.x;
        As[(cb+1)*64 + rl] = v.y;
        As[(cb+2)*64 + rl] = v.z;
        As[(cb+3)*64 + rl] = v.w;
    }
    for (int e = tid; e < 64*25; e += 256){
        int rl = e / 25, q = e % 25;
        *(float4*)&Ss[rl*D + q*4] = *(const float4*)&hcomb[(long)(r0 + al[rl])*D + q*4];
    }

    float acc[4][8];
    #pragma unroll
    for (int i=0;i<4;++i)
        #pragma unroll
        for (int j=0;j<8;++j) acc[i][j] = 0.f;

    for (int chunk = 0; chunk < 2; ++chunk){
        int c0 = chunk*52;
        __syncthreads();
        for (int e = tid; e < 52*128; e += 256){
            int d = e & 127, cc = e >> 7;
            int c = c0 + cc;
            Bs[cc*128 + d] = (c < D && d < D) ? glu1_w[c*D + d] : 0.f;
        }
        __syncthreads();
        for (int k = 0; k < 52; ++k){
            float4 a  = *(const float4*)&As[(c0+k)*64 + ty*4];
            float4 b0 = *(const float4*)&Bs[k*128 + tx*4];
            float4 b1 = *(const float4*)&Bs[k*128 + 64 + tx*4];
            float av[4] = {a.x,a.y,a.z,a.w};
            float bv[8] = {b0.x,b0.y,b0.z,b0.w,b1.x,b1.y,b1.z,b1.w};
            #pragma unroll
            for (int i=0;i<4;++i)
                #pragma unroll
                for (int j=0;j<8;++j) acc[i][j] += av[i]*bv[j];
        }
    }
    __syncthreads();

    float gl[8];
    #pragma unroll
    for (int j=0;j<8;++j){
        int d = (j<4) ? (tx*4+j) : (64 + tx*4 + (j-4));
        gl[j] = (d < D) ? gate[b*D + d] : 0.f;
    }
    float sp[8];
    #pragma unroll
    for (int j=0;j<8;++j) sp[j] = 0.f;
    #pragma unroll
    for (int i=0;i<4;++i){
        int rl = ty*4 + i;
        float p = 0.f;
        #pragma unroll
        for (int j=0;j<8;++j){
            int d = (j<4) ? (tx*4+j) : (64 + tx*4 + (j-4));
            float z = acc[i][j] + gl[j];
            float nh2 = 1.f/(1.f+expf(-z));
            p += nh2 * w2l[d];
        }
        #pragma unroll
        for (int off=1; off<16; off<<=1) p += __shfl_xor(p, off);
        float beta = p * mkl[rl];
        #pragma unroll
        for (int j=0;j<8;++j){
            int d = (j<4) ? (tx*4+j) : (64 + tx*4 + (j-4));
            if (d < D) sp[j] += beta * Ss[rl*D + d];
        }
    }
    #pragma unroll
    for (int j=0;j<8;++j){
        int d = (j<4) ? (tx*4+j) : (64 + tx*4 + (j-4));
        red[ty*128 + d] = sp[j];
    }
    __syncthreads();
    if (tid < 128){
        float s = 0.f;
        #pragma unroll
        for (int g=0; g<16; ++g) s += red[g*128 + tid];
        if (tid < D) sel_out[b*D + tid] = s;
    }
}

// ---------------- K5: score GEMM 128x128 tiles (8x8/thread) + fused online stats ----------
__global__ __launch_bounds__(256) void k5_score(const float* __restrict__ emb,
                                                const float* __restrict__ sel,
                                                float* __restrict__ out,
                                                float* __restrict__ pstats){
    __shared__ __align__(16) float As[52*128];
    __shared__ __align__(16) float Bs[52*128];
    int tid = threadIdx.x;
    int tx = tid & 15, ty = tid >> 4;
    int n0 = blockIdx.x * 128;
    int m0 = blockIdx.y * 128;

    float acc[8][8];
    #pragma unroll
    for (int i=0;i<8;++i)
        #pragma unroll
        for (int j=0;j<8;++j) acc[i][j] = 0.f;

    for (int chunk = 0; chunk < 2; ++chunk){
        int c0 = chunk*52;
        for (int e = tid; e < 128*13; e += 256){
            int rl = e & 127, cq = e >> 7;
            int cb = c0 + cq*4;
            float4 v = {0.f,0.f,0.f,0.f};
            if (cb < D) v = *(const float4*)&sel[(long)(m0+rl)*D + cb];
            As[(cq*4+0)*128 + rl] = v.x;
            As[(cq*4+1)*128 + rl] = v.y;
            As[(cq*4+2)*128 + rl] = v.z;
            As[(cq*4+3)*128 + rl] = v.w;
        }
        for (int e = tid; e < 128*13; e += 256){
            int nl = e & 127, cq = e >> 7;
            int cb = c0 + cq*4;
            int n = n0 + nl;
            float4 v = {0.f,0.f,0.f,0.f};
            if (cb < D && n < E) v = *(const float4*)&emb[(long)(1+n)*D + cb];
            Bs[(cq*4+0)*128 + nl] = v.x;
            Bs[(cq*4+1)*128 + nl] = v.y;
            Bs[(cq*4+2)*128 + nl] = v.z;
            Bs[(cq*4+3)*128 + nl] = v.w;
        }
        __syncthreads();
        for (int k = 0; k < 52; ++k){
            float4 a0v = *(const float4*)&As[k*128 + ty*8];
            float4 a1v = *(const float4*)&As[k*128 + ty*8 + 4];
            float4 b0 = *(const float4*)&Bs[k*128 + tx*4];
            float4 b1 = *(const float4*)&Bs[k*128 + 64 + tx*4];
            float av[8] = {a0v.x,a0v.y,a0v.z,a0v.w,a1v.x,a1v.y,a1v.z,a1v.w};
            float bv[8] = {b0.x,b0.y,b0.z,b0.w,b1.x,b1.y,b1.z,b1.w};
            #pragma unroll
            for (int i=0;i<8;++i)
                #pragma unroll
                for (int j=0;j<8;++j) acc[i][j] += av[i]*bv[j];
        }
        __syncthreads();
    }
    bool fullTile = (n0 + 128 <= E);
    #pragma unroll
    for (int i=0;i<8;++i){
        int m = m0 + ty*8 + i;
        long rowo = (long)m*E;
        if (fullTile){
            *(float4*)&out[rowo + n0 + tx*4]      = *(float4*)&acc[i][0];
            *(float4*)&out[rowo + n0 + 64 + tx*4] = *(float4*)&acc[i][4];
        } else {
            #pragma unroll
            for (int j=0;j<8;++j){
                int n = n0 + ((j<4) ? (tx*4+j) : (64 + tx*4 + (j-4)));
                if (n < E) out[rowo + n] = acc[i][j];
            }
        }
        float mx = -INFINITY, sm = 0.f;
        #pragma unroll
        for (int j=0;j<8;++j){
            int n = n0 + ((j<4) ? (tx*4+j) : (64 + tx*4 + (j-4)));
            if (n < E){
                float v = acc[i][j];
                if (v > mx){ sm = sm*expf(mx - v) + 1.f; mx = v; }
                else         sm += expf(v - mx);
            }
        }
        #pragma unroll
        for (int off=1; off<16; off<<=1){
            float mo = __shfl_xor(mx, off);
            float so = __shfl_xor(sm, off);
            float mm = fmaxf(mx, mo);
            float sn = 0.f;
            if (mx > -INFINITY) sn += sm*expf(mx-mm);
            if (mo > -INFINITY) sn += so*expf(mo-mm);
            mx = mm; sm = sn;
        }
        if (tx == 0){
            long o = ((long)m*NT5 + blockIdx.x)*2;
            pstats[o] = mx; pstats[o+1] = sm;
        }
    }
}

// ---------------- K7: combine per-row partial stats ----------------
__global__ __launch_bounds__(256) void k7_combine(const float* __restrict__ pstats,
                                                  float* __restrict__ MS){
    int row = blockIdx.x;
    int tid = threadIdx.x;
    float m = -INFINITY, s = 0.f;
    for (int t = tid; t < NT5; t += 256){
        long o = ((long)row*NT5 + t)*2;
        float m2 = pstats[o], s2 = pstats[o+1];
        float mm = fmaxf(m, m2);
        float sn = 0.f;
        if (m  > -INFINITY) sn += s *expf(m -mm);
        if (m2 > -INFINITY) sn += s2*expf(m2-mm);
        m = mm; s = sn;
    }
    __shared__ float ms[256], ss[256];
    ms[tid] = m; ss[tid] = s;
    __syncthreads();
    for (int off = 128; off >= 1; off >>= 1){
        if (tid < off){
            float m1 = ms[tid], s1 = ss[tid];
            float m2 = ms[tid+off], s2 = ss[tid+off];
            float mm = fmaxf(m1, m2);
            float sn = 0.f;
            if (m1 > -INFINITY) sn += s1*expf(m1-mm);
            if (m2 > -INFINITY) sn += s2*expf(m2-mm);
            ms[tid] = mm; ss[tid] = sn;
        }
        __syncthreads();
    }
    if (tid == 0){ MS[row*2] = ms[0]; MS[row*2+1] = 1.f/ss[0]; }
}

// ---------------- K8: normalize in place (float4 flat; B*E divisible by 4) ----------------
__global__ __launch_bounds__(256) void k8_norm(float* __restrict__ out,
                                               const float* __restrict__ MS){
    long base = ((long)blockIdx.x*256 + threadIdx.x)*4;
    const long total = (long)B*E;
    if (base < total){
        float4 v = *(float4*)&out[base];
        float r[4] = {v.x, v.y, v.z, v.w};
        #pragma unroll
        for (int c=0;c<4;++c){
            long el = base + c;
            int b = (int)(el / E);          // const-div -> mulhi
            r[c] = expf(r[c] - MS[b*2]) * MS[b*2+1];
        }
        v.x = r[0]; v.y = r[1]; v.z = r[2]; v.w = r[3];
        *(float4*)&out[base] = v;
    }
}

extern "C" void kernel_launch(void* const* d_in, const int* in_sizes, int n_in,
                              void* d_out, int out_size, void* d_ws, size_t ws_size,
                              hipStream_t stream) {
    const float* emb       = (const float*)d_in[0];
    const float* pos_table = (const float*)d_in[1];
    const float* w1        = (const float*)d_in[2];
    const float* w2        = (const float*)d_in[3];
    const float* glu1_w    = (const float*)d_in[4];
    const float* glu2_w    = (const float*)d_in[5];
    const float* glu2_b    = (const float*)d_in[6];
    const float* a0        = (const float*)d_in[7];
    const float* a1        = (const float*)d_in[8];
    const float* a2        = (const float*)d_in[9];
    const float* a3        = (const float*)d_in[10];
    const float* gw1       = (const float*)d_in[11];
    const float* gw2       = (const float*)d_in[12];
    const float* gw3       = (const float*)d_in[13];
    const float* num_w     = (const float*)d_in[14];
    const float* mask      = (const float*)d_in[15];
    const int*   alias_in  = (const int*)d_in[16];
    const int*   adj       = (const int*)d_in[17];
    const int*   items     = (const int*)d_in[18];
    const int*   seqf      = (const int*)d_in[19];
    const int*   adj_all   = (const int*)d_in[20];

    float* ws       = (float*)d_ws;
    float* h        = ws;                       // B*L*D
    float* hcomb    = h + B*L*D;                // B*L*D
    float* sess     = hcomb + B*L*D;            // B*D
    float* pos_part = sess + B*D;               // L*D
    float* sel      = pos_part + L*D;           // B*D
    float* att_l    = sel + B*D;                // M3A
    float* agg      = att_l + M3A;              // B*L*D (reused as nh1 after k3c)
    float* pstats   = agg + B*L*D;              // B*NT5*2
    float* MS       = pstats + B*NT5*2;         // B*2
    float* gate     = MS + B*2;                 // B*D
    float* nh1      = agg;                      // reuse (agg dead after k3c)

    float* out = (float*)d_out;

    k0_pos    <<<dim3(L), dim3(128), 0, stream>>>(pos_table, w1, pos_part);
    k1_gather <<<dim3(B), dim3(128), 0, stream>>>(emb, items, seqf, mask, h, sess);
    k2_local  <<<dim3(B), dim3(256), 0, stream>>>(h, adj, a0, a1, a2, a3, hcomb);
    k3a_logits<<<dim3(M3A/128), dim3(256), 0, stream>>>(emb, sess, items, adj_all, num_w,
                                                        gw1, gw2, att_l);
    k3b_agg   <<<dim3(B*L/2), dim3(256), 0, stream>>>(emb, items, adj_all, att_l, agg);
    k3c_hg    <<<dim3(B*L/64), dim3(256), 0, stream>>>(h, agg, gw3, hcomb);
    k4a_gate  <<<dim3(B), dim3(128), 0, stream>>>(hcomb, alias_in, mask, glu2_w, glu2_b, gate);
    k4b_nh1   <<<dim3(B), dim3(256), 0, stream>>>(hcomb, alias_in, w1, pos_part, nh1);
    k4c_select<<<dim3(B), dim3(256), 0, stream>>>(nh1, hcomb, alias_in, glu1_w, gate,
                                                  w2, mask, sel);
    k5_score  <<<dim3(NT5, 2), dim3(256), 0, stream>>>(emb, sel, out, pstats);
    k7_combine<<<dim3(B), dim3(256), 0, stream>>>(pstats, MS);
    k8_norm   <<<dim3((B*E/4 + 255)/256, 1), dim3(256), 0, stream>>>(out, MS);
}

// Round 11
// 622.686 us; speedup vs baseline: 1.7079x; 1.0323x over previous
//
#include <hip/hip_runtime.h>
#include <math.h>

#define B 256
#define L 64
#define D 100
#define S 12
#define NN 100000
#define E 99999
#define NEG -9e15f
#define LRELU 0.2f
#define M3A (B*L*S)          // 196608 rows for k3a
#define NT5 782              // ceil(E/128) col tiles in k5
#define CH 28                // K-chunk (K padded to 112 = 4*28); LDS = 2*14.3KB -> 5 blocks/CU

__device__ __forceinline__ float lrelu(float x){ return x > 0.f ? x : LRELU*x; }

// ---------------- K0: pos_part[l][d] = sum_c pos[l][c]*w1[c][d] ----------------
__global__ void k0_pos(const float* __restrict__ pos, const float* __restrict__ w1,
                       float* __restrict__ pos_part){
    int l = blockIdx.x; int d = threadIdx.x;
    if (d >= D) return;
    float acc = 0.f;
    for (int c = 0; c < D; ++c) acc += pos[l*D+c] * w1[c*D+d];
    pos_part[l*D+d] = acc;
}

// ---------------- K1: h = emb[items]; sess = masked mean of emb[seq_features] ----------------
__global__ void k1_gather(const float* __restrict__ emb, const int* __restrict__ items,
                          const int* __restrict__ seqf, const float* __restrict__ mask,
                          float* __restrict__ h, float* __restrict__ sess){
    int b = blockIdx.x; int tid = threadIdx.x;
    for (int e = tid; e < L*25; e += blockDim.x){
        int l = e / 25, q = e % 25;
        *(float4*)&h[(long)(b*L+l)*D + q*4] =
            *(const float4*)&emb[(long)items[b*L+l]*D + q*4];
    }
    if (tid < D){
        float acc = 0.f, msum = 0.f;
        for (int l = 0; l < L; ++l){
            float mk = mask[b*L+l];
            acc  += emb[(long)seqf[b*L+l]*D + tid] * mk;
            msum += mk;
        }
        sess[b*D+tid] = acc / msum;
    }
}

// ---------------- K2: local aggregator, one block per b ----------------
__global__ __launch_bounds__(256) void k2_local(const float* __restrict__ h,
                         const int* __restrict__ adj,
                         const float* __restrict__ a0, const float* __restrict__ a1,
                         const float* __restrict__ a2, const float* __restrict__ a3,
                         float* __restrict__ hcomb){
    __shared__ __align__(16) float Hd[L*132];
    __shared__ float Alr[L*66];
    __shared__ __align__(16) float a4s[D*4];
    int tid = threadIdx.x;
    int tx = tid & 15, ty = tid >> 4;
    int b = blockIdx.x;

    for (int t = tid; t < D; t += 256){
        a4s[t*4+0] = a0[t]; a4s[t*4+1] = a1[t]; a4s[t*4+2] = a2[t]; a4s[t*4+3] = a3[t];
    }
    for (int e = tid; e < L*D; e += 256){
        int i = e / D, d = e - i*D;
        Hd[i*132 + d] = h[(long)(b*L+i)*D + d];
    }
    for (int e = tid; e < L*32; e += 256){
        int i = e >> 5, c = D + (e & 31);
        Hd[i*132 + c] = 0.f;
    }
    __syncthreads();

    int ksel[4][4];
    #pragma unroll
    for (int i=0;i<4;++i)
        #pragma unroll
        for (int j=0;j<4;++j)
            ksel[i][j] = adj[((long)b*L + ty*4+i)*L + tx*4+j];

    float e0[4][4]={}, e1[4][4]={}, e2[4][4]={}, e3[4][4]={};
    for (int d = 0; d < D; ++d){
        float4 aw = *(const float4*)&a4s[d*4];
        float hi[4], hj[4];
        #pragma unroll
        for (int i=0;i<4;++i) hi[i] = Hd[(ty*4+i)*132 + d];
        #pragma unroll
        for (int j=0;j<4;++j) hj[j] = Hd[(tx*4+j)*132 + d];
        #pragma unroll
        for (int i=0;i<4;++i)
            #pragma unroll
            for (int j=0;j<4;++j){
                float p = hi[i]*hj[j];
                e0[i][j] += p*aw.x;
                e1[i][j] += p*aw.y;
                e2[i][j] += p*aw.z;
                e3[i][j] += p*aw.w;
            }
    }

    #pragma unroll
    for (int i=0;i<4;++i){
        float s[4];
        #pragma unroll
        for (int j=0;j<4;++j){
            int k = ksel[i][j];
            float ev = (k==1) ? e0[i][j] : (k==2) ? e1[i][j]
                     : (k==3) ? e2[i][j] : e3[i][j];
            s[j] = (k>=1 && k<=4) ? lrelu(ev) : NEG;
        }
        float m = fmaxf(fmaxf(s[0],s[1]), fmaxf(s[2],s[3]));
        #pragma unroll
        for (int off=1; off<16; off<<=1) m = fmaxf(m, __shfl_xor(m, off));
        float es[4], sum = 0.f;
        #pragma unroll
        for (int j=0;j<4;++j){ es[j] = expf(s[j]-m); sum += es[j]; }
        #pragma unroll
        for (int off=1; off<16; off<<=1) sum += __shfl_xor(sum, off);
        float inv = 1.f/sum;
        #pragma unroll
        for (int j=0;j<4;++j) Alr[(ty*4+i)*66 + tx*4+j] = es[j]*inv;
    }
    __syncthreads();

    float o[4][8];
    #pragma unroll
    for (int i=0;i<4;++i)
        #pragma unroll
        for (int jj=0;jj<8;++jj) o[i][jj] = 0.f;
    for (int j = 0; j < L; ++j){
        float al[4];
        #pragma unroll
        for (int i=0;i<4;++i) al[i] = Alr[(ty*4+i)*66 + j];
        float4 b0 = *(const float4*)&Hd[j*132 + tx*4];
        float4 b1 = *(const float4*)&Hd[j*132 + 64 + tx*4];
        float bv[8] = {b0.x,b0.y,b0.z,b0.w,b1.x,b1.y,b1.z,b1.w};
        #pragma unroll
        for (int i=0;i<4;++i)
            #pragma unroll
            for (int jj=0;jj<8;++jj) o[i][jj] += al[i]*bv[jj];
    }
    #pragma unroll
    for (int i=0;i<4;++i){
        int row = ty*4+i;
        #pragma unroll
        for (int jj=0;jj<8;++jj){
            int d = (jj<4) ? (tx*4+jj) : (64 + tx*4 + (jj-4));
            if (d < D) hcomb[(long)(b*L+row)*D + d] = o[i][jj];
        }
    }
}

// ---------------- K3a: att logits. 128x128(pad) tiles, 8x8/thread, K-chunk 28 ----------------
__global__ __launch_bounds__(256) void k3a_logits(const float* __restrict__ emb,
                          const float* __restrict__ sess,
                          const int* __restrict__ items, const int* __restrict__ adj_all,
                          const float* __restrict__ num_w,
                          const float* __restrict__ gw1, const float* __restrict__ gw2,
                          float* __restrict__ att_l){
    __shared__ __align__(16) float As[CH*128];
    __shared__ __align__(16) float Bs[CH*128];
    __shared__ int   idxr[128];
    __shared__ float nbwr[128];
    int tid = threadIdx.x;
    int tx = tid & 15, ty = tid >> 4;
    int r0 = blockIdx.x * 128;
    int b  = r0 / (L*S);

    if (tid < 128){
        int r = r0 + tid;
        int bl = r / S, s = r - bl*S;
        int it = items[bl];
        idxr[tid] = adj_all[it*S + s];
        nbwr[tid] = num_w[it*S + s];
    }
    __syncthreads();

    float acc[8][8];
    #pragma unroll
    for (int i=0;i<8;++i)
        #pragma unroll
        for (int j=0;j<8;++j) acc[i][j] = 0.f;

    for (int chunk = 0; chunk < 4; ++chunk){
        int c0 = chunk*CH;
        // stage A (k-major): ain[r0+rl][cb..cb+3]
        for (int e = tid; e < 128*7; e += 256){
            int rl = e & 127, cq = e >> 7;
            int cb = c0 + cq*4;
            float vx=0.f, vy=0.f, vz=0.f, vw=0.f;
            if (cb < D){
                const float4 v  = *(const float4*)&emb[(long)idxr[rl]*D + cb];
                const float4 sv = *(const float4*)&sess[(long)b*D + cb];
                vx = v.x*sv.x; vy = v.y*sv.y; vz = v.z*sv.z; vw = v.w*sv.w;
            } else if (cb == D){
                vx = nbwr[rl];
            }
            As[(cq*4+0)*128 + rl] = vx;
            As[(cq*4+1)*128 + rl] = vy;
            As[(cq*4+2)*128 + rl] = vz;
            As[(cq*4+3)*128 + rl] = vw;
        }
        // stage B: Bs[cc][d] = gw1[c0+cc][d]
        for (int e = tid; e < CH*128; e += 256){
            int d = e & 127, cc = e >> 7;
            int c = c0 + cc;
            Bs[cc*128 + d] = (c <= D && d < D) ? gw1[c*D + d] : 0.f;
        }
        __syncthreads();
        for (int k = 0; k < CH; ++k){
            float4 a0v = *(const float4*)&As[k*128 + ty*8];
            float4 a1v = *(const float4*)&As[k*128 + ty*8 + 4];
            float4 b0 = *(const float4*)&Bs[k*128 + tx*4];
            float4 b1 = *(const float4*)&Bs[k*128 + 64 + tx*4];
            float av[8] = {a0v.x,a0v.y,a0v.z,a0v.w,a1v.x,a1v.y,a1v.z,a1v.w};
            float bv[8] = {b0.x,b0.y,b0.z,b0.w,b1.x,b1.y,b1.z,b1.w};
            #pragma unroll
            for (int i=0;i<8;++i)
                #pragma unroll
                for (int j=0;j<8;++j) acc[i][j] += av[i]*bv[j];
        }
        __syncthreads();
    }
    float g[8];
    #pragma unroll
    for (int j=0;j<8;++j){
        int d = (j<4) ? (tx*4+j) : (64 + tx*4 + (j-4));
        g[j] = (d < D) ? gw2[d] : 0.f;
    }
    #pragma unroll
    for (int i=0;i<8;++i){
        float p = 0.f;
        #pragma unroll
        for (int j=0;j<8;++j) p += lrelu(acc[i][j]) * g[j];
        #pragma unroll
        for (int off=1; off<16; off<<=1) p += __shfl_xor(p, off);
        if (tx == 0) att_l[r0 + ty*8 + i] = p;
    }
}

// ---------------- K3b: softmax(12) + agg[bl][d] = sum_s att*nbr ----------------
__global__ __launch_bounds__(256) void k3b_agg(const float* __restrict__ emb,
                          const int* __restrict__ items, const int* __restrict__ adj_all,
                          const float* __restrict__ att_l,
                          float* __restrict__ agg){
    int p = blockIdx.x*2 + (threadIdx.x >> 7);   // bl index
    int t = threadIdx.x & 127;
    float lg[S];
    float m = -INFINITY;
    #pragma unroll
    for (int s=0;s<S;++s){ lg[s] = att_l[p*S + s]; m = fmaxf(m, lg[s]); }
    float sum = 0.f;
    #pragma unroll
    for (int s=0;s<S;++s){ lg[s] = expf(lg[s]-m); sum += lg[s]; }
    float inv = 1.f/sum;
    if (t < D){
        int it = items[p];
        float acc = 0.f;
        #pragma unroll
        for (int s=0;s<S;++s){
            int idx = adj_all[it*S + s];
            acc += lg[s]*inv * emb[(long)idx*D + t];
        }
        agg[p*D + t] = acc;
    }
}

// ---------------- K3c: hcomb += relu([h|agg] @ gw3). M=16384 K=208(pad) N=128(pad) ---------
__global__ __launch_bounds__(256) void k3c_hg(const float* __restrict__ h,
                          const float* __restrict__ agg, const float* __restrict__ gw3,
                          float* __restrict__ hcomb){
    __shared__ __align__(16) float As[52*64];
    __shared__ __align__(16) float Bs[52*128];
    int tid = threadIdx.x;
    int tx = tid & 15, ty = tid >> 4;
    int r0 = blockIdx.x * 64;

    float acc[4][8];
    #pragma unroll
    for (int i=0;i<4;++i)
        #pragma unroll
        for (int j=0;j<8;++j) acc[i][j] = 0.f;

    for (int chunk = 0; chunk < 4; ++chunk){
        int c0 = chunk*52;
        for (int e = tid; e < 64*13; e += 256){
            int rl = e & 63, cq = e >> 6;
            int cb = c0 + cq*4;
            float4 v = {0.f,0.f,0.f,0.f};
            if (cb < D)            v = *(const float4*)&h[(long)(r0+rl)*D + cb];
            else if (cb < 2*D)     v = *(const float4*)&agg[(long)(r0+rl)*D + (cb-D)];
            As[(cq*4+0)*64 + rl] = v.x;
            As[(cq*4+1)*64 + rl] = v.y;
            As[(cq*4+2)*64 + rl] = v.z;
            As[(cq*4+3)*64 + rl] = v.w;
        }
        for (int e = tid; e < 52*128; e += 256){
            int d = e & 127, cc = e >> 7;
            int c = c0 + cc;
            Bs[cc*128 + d] = (c < 2*D && d < D) ? gw3[c*D + d] : 0.f;
        }
        __syncthreads();
        for (int k = 0; k < 52; ++k){
            float4 a  = *(const float4*)&As[k*64 + ty*4];
            float4 b0 = *(const float4*)&Bs[k*128 + tx*4];
            float4 b1 = *(const float4*)&Bs[k*128 + 64 + tx*4];
            float av[4] = {a.x,a.y,a.z,a.w};
            float bv[8] = {b0.x,b0.y,b0.z,b0.w,b1.x,b1.y,b1.z,b1.w};
            #pragma unroll
            for (int i=0;i<4;++i)
                #pragma unroll
                for (int j=0;j<8;++j) acc[i][j] += av[i]*bv[j];
        }
        __syncthreads();
    }
    #pragma unroll
    for (int i=0;i<4;++i){
        int r = r0 + ty*4 + i;
        #pragma unroll
        for (int j=0;j<8;++j){
            int d = (j<4) ? (tx*4+j) : (64 + tx*4 + (j-4));
            if (d < D){
                long o = (long)r*D + d;
                hcomb[o] += fmaxf(acc[i][j], 0.f);
            }
        }
    }
}

// ---------------- K4a: per-b hs + gate ----------------
__global__ __launch_bounds__(128) void k4a_gate(const float* __restrict__ hcomb,
                          const int* __restrict__ alias_in, const float* __restrict__ mask,
                          const float* __restrict__ glu2_w, const float* __restrict__ glu2_b,
                          float* __restrict__ gate){
    int b = blockIdx.x; int tid = threadIdx.x;
    __shared__ float hsl[D];
    __shared__ float mkl[L];
    __shared__ int   al[L];
    if (tid < L){ al[tid] = alias_in[b*L+tid]; mkl[tid] = mask[b*L+tid]; }
    __syncthreads();
    if (tid < D){
        float acc = 0.f, msum = 0.f;
        for (int l = 0; l < L; ++l){
            acc  += hcomb[(long)(b*L + al[l])*D + tid] * mkl[l];
            msum += mkl[l];
        }
        hsl[tid] = acc / msum;
    }
    __syncthreads();
    if (tid < D){
        float g = glu2_b[tid];
        for (int c = 0; c < D; ++c) g += hsl[c]*glu2_w[c*D+tid];
        gate[b*D+tid] = g;
    }
}

// ---------------- K4b: nh1 = tanh(seqh @ w1[D:] + pos_part[l]) ----------------
__global__ __launch_bounds__(256) void k4b_nh1(const float* __restrict__ hcomb,
                          const int* __restrict__ alias_in,
                          const float* __restrict__ w1, const float* __restrict__ pos_part,
                          float* __restrict__ nh1){
    __shared__ __align__(16) float As[52*64];
    __shared__ __align__(16) float Bs[52*128];
    __shared__ int al[64];
    int tid = threadIdx.x;
    int tx = tid & 15, ty = tid >> 4;
    int b = blockIdx.x;
    int r0 = b * 64;

    if (tid < 64) al[tid] = alias_in[r0 + tid];
    __syncthreads();

    float acc[4][8];
    #pragma unroll
    for (int i=0;i<4;++i)
        #pragma unroll
        for (int j=0;j<8;++j) acc[i][j] = 0.f;

    for (int chunk = 0; chunk < 2; ++chunk){
        int c0 = chunk*52;
        for (int e = tid; e < 64*13; e += 256){
            int rl = e & 63, cq = e >> 6;
            int cb = c0 + cq*4;
            float4 v = {0.f,0.f,0.f,0.f};
            if (cb < D) v = *(const float4*)&hcomb[(long)(r0 + al[rl])*D + cb];
            As[(cq*4+0)*64 + rl] = v.x;
            As[(cq*4+1)*64 + rl] = v.y;
            As[(cq*4+2)*64 + rl] = v.z;
            As[(cq*4+3)*64 + rl] = v.w;
        }
        for (int e = tid; e < 52*128; e += 256){
            int d = e & 127, cc = e >> 7;
            int c = c0 + cc;
            Bs[cc*128 + d] = (c < D && d < D) ? w1[(D+c)*D + d] : 0.f;
        }
        __syncthreads();
        for (int k = 0; k < 52; ++k){
            float4 a  = *(const float4*)&As[k*64 + ty*4];
            float4 b0 = *(const float4*)&Bs[k*128 + tx*4];
            float4 b1 = *(const float4*)&Bs[k*128 + 64 + tx*4];
            float av[4] = {a.x,a.y,a.z,a.w};
            float bv[8] = {b0.x,b0.y,b0.z,b0.w,b1.x,b1.y,b1.z,b1.w};
            #pragma unroll
            for (int i=0;i<4;++i)
                #pragma unroll
                for (int j=0;j<8;++j) acc[i][j] += av[i]*bv[j];
        }
        __syncthreads();
    }
    #pragma unroll
    for (int i=0;i<4;++i){
        int rl = ty*4 + i;
        #pragma unroll
        for (int j=0;j<8;++j){
            int d = (j<4) ? (tx*4+j) : (64 + tx*4 + (j-4));
            if (d < D){
                float v = tanhf(acc[i][j] + pos_part[rl*D + d]);
                nh1[(long)(r0+rl)*D + d] = v;
            }
        }
    }
}

// ---------------- K4c: nh2=sigmoid(nh1@glu1+gate); beta=(nh2.w2)*mask; select=sum beta*seqh --
__global__ __launch_bounds__(256) void k4c_select(const float* __restrict__ nh1,
                          const float* __restrict__ hcomb, const int* __restrict__ alias_in,
                          const float* __restrict__ glu1_w, const float* __restrict__ gate,
                          const float* __restrict__ w2, const float* __restrict__ mask,
                          float* __restrict__ sel_out){
    __shared__ __align__(16) float As[104*64];
    __shared__ __align__(16) float Bs[52*128];
    __shared__ __align__(16) float Ss[64*D];
    __shared__ float red[16*128];
    __shared__ float w2l[128];
    __shared__ float mkl[64];
    __shared__ int   al[64];
    int tid = threadIdx.x;
    int tx = tid & 15, ty = tid >> 4;
    int b = blockIdx.x;
    int r0 = b * 64;

    if (tid < 64){ al[tid] = alias_in[r0 + tid]; mkl[tid] = mask[r0 + tid]; }
    if (tid < 128) w2l[tid] = (tid < D) ? w2[tid] : 0.f;
    __syncthreads();

    for (int e = tid; e < 64*26; e += 256){
        int rl = e & 63, cq = e >> 6;
        int cb = cq*4;
        float4 v = {0.f,0.f,0.f,0.f};
        if (cb < D) v = *(const float4*)&nh1[(long)(r0+rl)*D + cb];
        As[(cb+0)*64 + rl] = v.x;
        As[(cb+1)*64 + rl] = v.y;
        As[(cb+2)*64 + rl] = v.z;
        As[(cb+3)*64 + rl] = v.w;
    }
    for (int e = tid; e < 64*25; e += 256){
        int rl = e / 25, q = e % 25;
        *(float4*)&Ss[rl*D + q*4] = *(const float4*)&hcomb[(long)(r0 + al[rl])*D + q*4];
    }

    float acc[4][8];
    #pragma unroll
    for (int i=0;i<4;++i)
        #pragma unroll
        for (int j=0;j<8;++j) acc[i][j] = 0.f;

    for (int chunk = 0; chunk < 2; ++chunk){
        int c0 = chunk*52;
        __syncthreads();
        for (int e = tid; e < 52*128; e += 256){
            int d = e & 127, cc = e >> 7;
            int c = c0 + cc;
            Bs[cc*128 + d] = (c < D && d < D) ? glu1_w[c*D + d] : 0.f;
        }
        __syncthreads();
        for (int k = 0; k < 52; ++k){
            float4 a  = *(const float4*)&As[(c0+k)*64 + ty*4];
            float4 b0 = *(const float4*)&Bs[k*128 + tx*4];
            float4 b1 = *(const float4*)&Bs[k*128 + 64 + tx*4];
            float av[4] = {a.x,a.y,a.z,a.w};
            float bv[8] = {b0.x,b0.y,b0.z,b0.w,b1.x,b1.y,b1.z,b1.w};
            #pragma unroll
            for (int i=0;i<4;++i)
                #pragma unroll
                for (int j=0;j<8;++j) acc[i][j] += av[i]*bv[j];
        }
    }
    __syncthreads();

    float gl[8];
    #pragma unroll
    for (int j=0;j<8;++j){
        int d = (j<4) ? (tx*4+j) : (64 + tx*4 + (j-4));
        gl[j] = (d < D) ? gate[b*D + d] : 0.f;
    }
    float sp[8];
    #pragma unroll
    for (int j=0;j<8;++j) sp[j] = 0.f;
    #pragma unroll
    for (int i=0;i<4;++i){
        int rl = ty*4 + i;
        float p = 0.f;
        #pragma unroll
        for (int j=0;j<8;++j){
            int d = (j<4) ? (tx*4+j) : (64 + tx*4 + (j-4));
            float z = acc[i][j] + gl[j];
            float nh2 = 1.f/(1.f+expf(-z));
            p += nh2 * w2l[d];
        }
        #pragma unroll
        for (int off=1; off<16; off<<=1) p += __shfl_xor(p, off);
        float beta = p * mkl[rl];
        #pragma unroll
        for (int j=0;j<8;++j){
            int d = (j<4) ? (tx*4+j) : (64 + tx*4 + (j-4));
            if (d < D) sp[j] += beta * Ss[rl*D + d];
        }
    }
    #pragma unroll
    for (int j=0;j<8;++j){
        int d = (j<4) ? (tx*4+j) : (64 + tx*4 + (j-4));
        red[ty*128 + d] = sp[j];
    }
    __syncthreads();
    if (tid < 128){
        float s = 0.f;
        #pragma unroll
        for (int g=0; g<16; ++g) s += red[g*128 + tid];
        if (tid < D) sel_out[b*D + tid] = s;
    }
}

// ---------------- K5: score GEMM 128x128 tiles, 8x8/thread, K-chunk 28 + fused stats --------
__global__ __launch_bounds__(256) void k5_score(const float* __restrict__ emb,
                                                const float* __restrict__ sel,
                                                float* __restrict__ out,
                                                float* __restrict__ pstats){
    __shared__ __align__(16) float As[CH*128];
    __shared__ __align__(16) float Bs[CH*128];
    int tid = threadIdx.x;
    int tx = tid & 15, ty = tid >> 4;
    int n0 = blockIdx.x * 128;
    int m0 = blockIdx.y * 128;

    float acc[8][8];
    #pragma unroll
    for (int i=0;i<8;++i)
        #pragma unroll
        for (int j=0;j<8;++j) acc[i][j] = 0.f;

    for (int chunk = 0; chunk < 4; ++chunk){
        int c0 = chunk*CH;
        for (int e = tid; e < 128*7; e += 256){
            int rl = e & 127, cq = e >> 7;
            int cb = c0 + cq*4;
            float4 v = {0.f,0.f,0.f,0.f};
            if (cb < D) v = *(const float4*)&sel[(long)(m0+rl)*D + cb];
            As[(cq*4+0)*128 + rl] = v.x;
            As[(cq*4+1)*128 + rl] = v.y;
            As[(cq*4+2)*128 + rl] = v.z;
            As[(cq*4+3)*128 + rl] = v.w;
        }
        for (int e = tid; e < 128*7; e += 256){
            int nl = e & 127, cq = e >> 7;
            int cb = c0 + cq*4;
            int n = n0 + nl;
            float4 v = {0.f,0.f,0.f,0.f};
            if (cb < D && n < E) v = *(const float4*)&emb[(long)(1+n)*D + cb];
            Bs[(cq*4+0)*128 + nl] = v.x;
            Bs[(cq*4+1)*128 + nl] = v.y;
            Bs[(cq*4+2)*128 + nl] = v.z;
            Bs[(cq*4+3)*128 + nl] = v.w;
        }
        __syncthreads();
        for (int k = 0; k < CH; ++k){
            float4 a0v = *(const float4*)&As[k*128 + ty*8];
            float4 a1v = *(const float4*)&As[k*128 + ty*8 + 4];
            float4 b0 = *(const float4*)&Bs[k*128 + tx*4];
            float4 b1 = *(const float4*)&Bs[k*128 + 64 + tx*4];
            float av[8] = {a0v.x,a0v.y,a0v.z,a0v.w,a1v.x,a1v.y,a1v.z,a1v.w};
            float bv[8] = {b0.x,b0.y,b0.z,b0.w,b1.x,b1.y,b1.z,b1.w};
            #pragma unroll
            for (int i=0;i<8;++i)
                #pragma unroll
                for (int j=0;j<8;++j) acc[i][j] += av[i]*bv[j];
        }
        __syncthreads();
    }
    bool fullTile = (n0 + 128 <= E);
    #pragma unroll
    for (int i=0;i<8;++i){
        int m = m0 + ty*8 + i;
        long rowo = (long)m*E;
        if (fullTile){
            *(float4*)&out[rowo + n0 + tx*4]      = *(float4*)&acc[i][0];
            *(float4*)&out[rowo + n0 + 64 + tx*4] = *(float4*)&acc[i][4];
        } else {
            #pragma unroll
            for (int j=0;j<8;++j){
                int n = n0 + ((j<4) ? (tx*4+j) : (64 + tx*4 + (j-4)));
                if (n < E) out[rowo + n] = acc[i][j];
            }
        }
        float mx = -INFINITY, sm = 0.f;
        #pragma unroll
        for (int j=0;j<8;++j){
            int n = n0 + ((j<4) ? (tx*4+j) : (64 + tx*4 + (j-4)));
            if (n < E){
                float v = acc[i][j];
                if (v > mx){ sm = sm*expf(mx - v) + 1.f; mx = v; }
                else         sm += expf(v - mx);
            }
        }
        #pragma unroll
        for (int off=1; off<16; off<<=1){
            float mo = __shfl_xor(mx, off);
            float so = __shfl_xor(sm, off);
            float mm = fmaxf(mx, mo);
            float sn = 0.f;
            if (mx > -INFINITY) sn += sm*expf(mx-mm);
            if (mo > -INFINITY) sn += so*expf(mo-mm);
            mx = mm; sm = sn;
        }
        if (tx == 0){
            long o = ((long)m*NT5 + blockIdx.x)*2;
            pstats[o] = mx; pstats[o+1] = sm;
        }
    }
}

// ---------------- K7: combine per-row partial stats ----------------
__global__ __launch_bounds__(256) void k7_combine(const float* __restrict__ pstats,
                                                  float* __restrict__ MS){
    int row = blockIdx.x;
    int tid = threadIdx.x;
    float m = -INFINITY, s = 0.f;
    for (int t = tid; t < NT5; t += 256){
        long o = ((long)row*NT5 + t)*2;
        float m2 = pstats[o], s2 = pstats[o+1];
        float mm = fmaxf(m, m2);
        float sn = 0.f;
        if (m  > -INFINITY) sn += s *expf(m -mm);
        if (m2 > -INFINITY) sn += s2*expf(m2-mm);
        m = mm; s = sn;
    }
    __shared__ float ms[256], ss[256];
    ms[tid] = m; ss[tid] = s;
    __syncthreads();
    for (int off = 128; off >= 1; off >>= 1){
        if (tid < off){
            float m1 = ms[tid], s1 = ss[tid];
            float m2 = ms[tid+off], s2 = ss[tid+off];
            float mm = fmaxf(m1, m2);
            float sn = 0.f;
            if (m1 > -INFINITY) sn += s1*expf(m1-mm);
            if (m2 > -INFINITY) sn += s2*expf(m2-mm);
            ms[tid] = mm; ss[tid] = sn;
        }
        __syncthreads();
    }
    if (tid == 0){ MS[row*2] = ms[0]; MS[row*2+1] = 1.f/ss[0]; }
}

// ---------------- K8: normalize in place (float4 flat; B*E divisible by 4) ----------------
__global__ __launch_bounds__(256) void k8_norm(float* __restrict__ out,
                                               const float* __restrict__ MS){
    long base = ((long)blockIdx.x*256 + threadIdx.x)*4;
    const long total = (long)B*E;
    if (base < total){
        float4 v = *(float4*)&out[base];
        float r[4] = {v.x, v.y, v.z, v.w};
        #pragma unroll
        for (int c=0;c<4;++c){
            long el = base + c;
            int b = (int)(el / E);          // const-div -> mulhi
            r[c] = expf(r[c] - MS[b*2]) * MS[b*2+1];
        }
        v.x = r[0]; v.y = r[1]; v.z = r[2]; v.w = r[3];
        *(float4*)&out[base] = v;
    }
}

extern "C" void kernel_launch(void* const* d_in, const int* in_sizes, int n_in,
                              void* d_out, int out_size, void* d_ws, size_t ws_size,
                              hipStream_t stream) {
    const float* emb       = (const float*)d_in[0];
    const float* pos_table = (const float*)d_in[1];
    const float* w1        = (const float*)d_in[2];
    const float* w2        = (const float*)d_in[3];
    const float* glu1_w    = (const float*)d_in[4];
    const float* glu2_w    = (const float*)d_in[5];
    const float* glu2_b    = (const float*)d_in[6];
    const float* a0        = (const float*)d_in[7];
    const float* a1        = (const float*)d_in[8];
    const float* a2        = (const float*)d_in[9];
    const float* a3        = (const float*)d_in[10];
    const float* gw1       = (const float*)d_in[11];
    const float* gw2       = (const float*)d_in[12];
    const float* gw3       = (const float*)d_in[13];
    const float* num_w     = (const float*)d_in[14];
    const float* mask      = (const float*)d_in[15];
    const int*   alias_in  = (const int*)d_in[16];
    const int*   adj       = (const int*)d_in[17];
    const int*   items     = (const int*)d_in[18];
    const int*   seqf      = (const int*)d_in[19];
    const int*   adj_all   = (const int*)d_in[20];

    float* ws       = (float*)d_ws;
    float* h        = ws;                       // B*L*D
    float* hcomb    = h + B*L*D;                // B*L*D
    float* sess     = hcomb + B*L*D;            // B*D
    float* pos_part = sess + B*D;               // L*D
    float* sel      = pos_part + L*D;           // B*D
    float* att_l    = sel + B*D;                // M3A
    float* agg      = att_l + M3A;              // B*L*D (reused as nh1 after k3c)
    float* pstats   = agg + B*L*D;              // B*NT5*2
    float* MS       = pstats + B*NT5*2;         // B*2
    float* gate     = MS + B*2;                 // B*D
    float* nh1      = agg;                      // reuse (agg dead after k3c)

    float* out = (float*)d_out;

    k0_pos    <<<dim3(L), dim3(128), 0, stream>>>(pos_table, w1, pos_part);
    k1_gather <<<dim3(B), dim3(128), 0, stream>>>(emb, items, seqf, mask, h, sess);
    k2_local  <<<dim3(B), dim3(256), 0, stream>>>(h, adj, a0, a1, a2, a3, hcomb);
    k3a_logits<<<dim3(M3A/128), dim3(256), 0, stream>>>(emb, sess, items, adj_all, num_w,
                                                        gw1, gw2, att_l);
    k3b_agg   <<<dim3(B*L/2), dim3(256), 0, stream>>>(emb, items, adj_all, att_l, agg);
    k3c_hg    <<<dim3(B*L/64), dim3(256), 0, stream>>>(h, agg, gw3, hcomb);
    k4a_gate  <<<dim3(B), dim3(128), 0, stream>>>(hcomb, alias_in, mask, glu2_w, glu2_b, gate);
    k4b_nh1   <<<dim3(B), dim3(256), 0, stream>>>(hcomb, alias_in, w1, pos_part, nh1);
    k4c_select<<<dim3(B), dim3(256), 0, stream>>>(nh1, hcomb, alias_in, glu1_w, gate,
                                                  w2, mask, sel);
    k5_score  <<<dim3(NT5, 2), dim3(256), 0, stream>>>(emb, sel, out, pstats);
    k7_combine<<<dim3(B), dim3(256), 0, stream>>>(pstats, MS);
    k8_norm   <<<dim3((B*E/4 + 255)/256, 1), dim3(256), 0, stream>>>(out, MS);
}